// Round 10
// baseline (758.841 us; speedup 1.0000x reference)
//
#include <hip/hip_runtime.h>
#include <hip/hip_cooperative_groups.h>
#include <math.h>

namespace cg = cooperative_groups;

#define NB 512
#define LIN 640
#define NLEADS 3
#define L1O 322
#define L2O 161
#define L3O 79
#define C1N 64
#define C2N 128
#define C3N 256
#define FLATSZ 20224   // 256*79
#define NUMK 100
#define DIMK 5
#define SPLITK 16
#define COOPG 1024

typedef __attribute__((ext_vector_type(8))) short short8;
typedef __attribute__((ext_vector_type(4))) float f32x4;

__device__ __forceinline__ unsigned short f2bf(float x){
  unsigned u = __builtin_bit_cast(unsigned, x);
  unsigned r = u + 0x7FFFu + ((u >> 16) & 1u);
  return (unsigned short)(r >> 16);
}
__device__ __forceinline__ float bf2f(unsigned short x){
  unsigned u = ((unsigned)x) << 16;
  return __builtin_bit_cast(float, u);
}

__device__ __forceinline__ float block_reduce_sum(float val, float* red){
#pragma unroll
  for(int off=32; off>0; off>>=1) val += __shfl_down(val, off, 64);
  int lane = threadIdx.x & 63;
  int wv = threadIdx.x >> 6;
  if(lane==0) red[wv] = val;
  __syncthreads();
  int nw = blockDim.x >> 6;
  float r = red[0];
  for(int i=1;i<nw;i++) r += red[i];
  __syncthreads();
  return r;
}

// ---------- coop1: [sn_pass1 || mbw_transpose] -> sync -> sn_pass2 -> sync -> wprep ----------
// r20: collapse 4 dispatches + memset into one cooperative kernel. Atomics replaced by
// partial-sum slots (ss_part[8], Sun_part[112]) so no pre-zeroing is needed.
__global__ __launch_bounds__(256)
void coop1_kernel(const float* __restrict__ w1, const float* __restrict__ u1,
                  const float* __restrict__ w2, const float* __restrict__ u2,
                  const float* __restrict__ w3, const float* __restrict__ u3,
                  float* __restrict__ v_all, float* __restrict__ ss_part,
                  float* __restrict__ Sun_part, const float* __restrict__ mbw,
                  unsigned short* __restrict__ mbwT,
                  unsigned short* __restrict__ w1p, unsigned short* __restrict__ w2p,
                  unsigned short* __restrict__ w3p){
  __shared__ float red[4];
  __shared__ unsigned short tile[32][36];
  cg::grid_group grid = cg::this_grid();
  int bid = blockIdx.x, tid = threadIdx.x;

  // ---- phase A1: sn_pass1 (blocks 0..7), verbatim body, partial-sum output ----
  if(bid < 8){
    int b = bid;
    const float* w; const float* u; int O, C, off, c;
    if(b==0){ w=w1; u=u1; O=64;  C=15;   off=0;   c=tid; }
    else if(b<3){ w=w2; u=u2; O=128; C=448; off=16;  c=(b-1)*256+tid; }
    else { w=w3; u=u3; O=256; C=1152; off=464; c=(b-3)*256+tid; }
    float vv = 0.f;
    if(c < C){
      for(int o=0;o<O;o+=4){
        vv += w[(o+0)*C+c]*u[o+0] + w[(o+1)*C+c]*u[o+1]
            + w[(o+2)*C+c]*u[o+2] + w[(o+3)*C+c]*u[o+3];
      }
      v_all[off + c] = vv;
    }
    float ps = (c < C) ? vv*vv : 0.f;
    float tot = block_reduce_sum(ps, red);
    if(tid==0) ss_part[b] = tot;
  }

  // ---- phase A2: mbw_transpose (all blocks, grid-stride over 632x16 tiles) ----
  for(int tt = bid; tt < 632*16; tt += COOPG){
    int k0 = (tt % 632)*32, n0 = (tt / 632)*32;
    int r = tid >> 3, c4 = (tid & 7) * 4;
    int nbase = n0 + c4;
    if(nbase + 3 < 500){
      float4 v = *(const float4*)(mbw + (size_t)(k0+r)*500 + nbase);
      tile[r][c4+0] = f2bf(v.x);
      tile[r][c4+1] = f2bf(v.y);
      tile[r][c4+2] = f2bf(v.z);
      tile[r][c4+3] = f2bf(v.w);
    } else {
#pragma unroll
      for(int j=0;j<4;j++){
        int nn = nbase + j;
        float v = (nn < 500) ? mbw[(size_t)(k0+r)*500 + nn] : 0.f;
        tile[r][c4+j] = f2bf(v);
      }
    }
    __syncthreads();
    int nl = tid >> 3, kq = (tid & 7) * 4;
    unsigned short t0 = tile[kq+0][nl], t1 = tile[kq+1][nl];
    unsigned short t2 = tile[kq+2][nl], t3 = tile[kq+3][nl];
    uint2 p;
    p.x = (unsigned)t0 | ((unsigned)t1 << 16);
    p.y = (unsigned)t2 | ((unsigned)t3 << 16);
    *(uint2*)(mbwT + (size_t)(n0+nl)*FLATSZ + k0 + kq) = p;
    __syncthreads();   // tile reuse on next trip
  }

  grid.sync();

  // ---- phase B: sn_pass2 (blocks 0..111), per-block partial Sun ----
  if(bid < 112){
    int b = bid;
    int lane = tid & 63, wv = tid >> 6;
    const float* w; int C, off, o;
    if(b < 16){ w=w1; C=15;   off=0;   o=b*4+wv; }
    else if(b < 48){ w=w2; C=448; off=16;  o=(b-16)*4+wv; }
    else { w=w3; C=1152; off=464; o=(b-48)*4+wv; }
    float t = 0.f;
    for(int c=lane; c<C; c+=64) t += w[o*C+c]*v_all[off+c];
#pragma unroll
    for(int s=32; s>0; s>>=1) t += __shfl_down(t, s, 64);
    if(lane==0) red[wv] = t*t;
    __syncthreads();
    if(tid==0) Sun_part[b] = red[0] + red[1] + red[2] + red[3];
  }

  grid.sync();

  // ---- phase C: wprep (grid-stride over 294,912 elems), scales from partials ----
  float ssv0 = ss_part[0];
  float ssv1 = ss_part[1] + ss_part[2];
  float ssv2 = ss_part[3] + ss_part[4] + ss_part[5] + ss_part[6] + ss_part[7];
  float Sunv[3] = {0.f, 0.f, 0.f};
  for(int b=0;b<112;b++){
    int widx = (b<16) ? 0 : ((b<48) ? 1 : 2);
    Sunv[widx] += Sun_part[b];
  }
  float ssv[3] = {ssv0, ssv1, ssv2};
  float sc[3];
#pragma unroll
  for(int i=0;i<3;i++){
    float inv = 1.f/(sqrtf(ssv[i])+1e-12f);
    float S = Sunv[i]*inv*inv;
    sc[i] = (sqrtf(S)+1e-12f)/S;
  }
  for(int idx = bid*256 + tid; idx < C3N*1152; idx += COOPG*256){
    if(idx < C1N*32){
      int o = idx >> 5, kk = idx & 31;
      w1p[idx] = (kk < 15) ? f2bf(w1[o*15+kk]*sc[0]) : 0;
    }
    if(idx < C2N*448){
      int o = idx / 448, k2 = idx - o*448;
      int r = k2 >> 6, i = k2 & 63;
      w2p[idx] = f2bf(w2[o*448 + i*7 + r]*sc[1]);
    }
    if(idx < C3N*1152){
      int o = idx / 1152, k2 = idx - o*1152;
      int r = k2 >> 7, i = k2 & 127;
      w3p[idx] = f2bf(w3[o*1152 + i*9 + r]*sc[2]);
    }
  }
}

// ---------- FUSED conv1+conv2+conv3 (r17, unchanged) ----------
__global__ __launch_bounds__(256, 2)
void conv123_mfma(const float* __restrict__ ecg, const unsigned short* __restrict__ w1p,
                  const float* __restrict__ b1, const unsigned short* __restrict__ w2p,
                  const float* __restrict__ b2, const unsigned short* __restrict__ w3p,
                  const float* __restrict__ b3, unsigned short* __restrict__ flatbf){
  __shared__ unsigned short y2buf[22712];   // even slab 84*136 @0; odd slab 83*136 @11424
  __shared__ unsigned short slabs[13600];   // y1 parity slabs (per tile): even [100][68] @0, odd @6800
  __shared__ unsigned short B1s[3328];      // [208][16] u16 — conv1 im2col (kk 0..15; 15=pad)
  int n = blockIdx.x, tid = threadIdx.x;
  int lane = tid & 63, w = tid >> 6;

  if(tid < 136){
    y2buf[tid] = 0;
    y2buf[82*136 + tid] = 0;
    y2buf[83*136 + tid] = 0;
    y2buf[11424 + tid] = 0;
    y2buf[11424 + 81*136 + tid] = 0;
    y2buf[11424 + 82*136 + tid] = 0;
  }

  const float* eb = ecg + (size_t)n*LIN*NLEADS;
  f32x4 zero4 = {0.f,0.f,0.f,0.f};

  for(int tile=0; tile<2; tile++){
    int c0    = tile ? 189 : 0;
    int tbase = tile ? 96  : 0;
    int suboff= tile ? -94 : 2;

    __syncthreads();
    {
      uint4 z = {0u,0u,0u,0u};
      uint4* zd = (uint4*)slabs;
#pragma unroll
      for(int q=0;q<7;q++){
        int f = q*256 + tid;
        if(f < 1700) zd[f] = z;
      }
    }
    if(tid < 208){
      int t1 = c0 + tid;
      int p0 = 2*t1 - 4;
      unsigned short row16[16];
      row16[15] = 0;
      if(p0 >= 0 && p0 <= 635){
        const float* f = eb + p0*NLEADS;
#pragma unroll
        for(int rp=0; rp<5; rp++)
#pragma unroll
          for(int i=0;i<3;i++)
            row16[i*5+rp] = f2bf(f[3*rp+i]);
      } else {
#pragma unroll
        for(int rp=0; rp<5; rp++){
          int p = p0 + rp;
          bool ok = (unsigned)p < (unsigned)LIN;
#pragma unroll
          for(int i=0;i<3;i++)
            row16[i*5+rp] = ok ? f2bf(eb[p*NLEADS+i]) : (unsigned short)0;
        }
      }
      unsigned* dst = (unsigned*)(B1s + tid*16);
#pragma unroll
      for(int q=0;q<8;q++)
        dst[q] = (unsigned)row16[2*q] | ((unsigned)row16[2*q+1] << 16);
    }
    __syncthreads();

    // conv1 MFMA -> y1 parity slabs
    {
      short8 a1 = *(const short8*)(w1p + ((w*16 + (lane&15))<<5) + (lane>>4)*8);
      int cfrag = lane >> 4;
#pragma unroll
      for(int half=0; half<2; half++){
        int nt0 = half*7, ntc = half ? 6 : 7;
        f32x4 c1[7];
        for(int j=0;j<ntc;j++){
          int tp = (nt0+j)*16 + (lane&15);
          short8 b = {0,0,0,0,0,0,0,0};
          if(cfrag < 2) b = *(const short8*)(B1s + tp*16 + cfrag*8);
          c1[j] = __builtin_amdgcn_mfma_f32_16x16x32_bf16(a1, b, zero4, 0, 0, 0);
        }
#pragma unroll
        for(int reg=0;reg<4;reg++){
          int o = w*16 + (lane>>4)*4 + reg;
          float bias = b1[o];
          for(int j=0;j<ntc;j++){
            int tp = (nt0+j)*16 + (lane&15);
            int t1 = c0 + tp;
            int sub = (t1>>1) + suboff;
            if(t1 < L1O && sub < 100){
              float v = c1[j][reg] + bias;
              v = v>=0.f ? v : 0.2f*v;
              slabs[((t1&1)?6800:0) + sub*68 + o] = f2bf(v);
            }
          }
        }
      }
    }
    __syncthreads();

    // conv2 K-loop -> epilogue into y2buf
    f32x4 acc[2][6];
#pragma unroll
    for(int i=0;i<2;i++)
#pragma unroll
      for(int j=0;j<6;j++) acc[i][j] = zero4;

    const unsigned short* w2base = w2p + ((size_t)(w*2*16 + (lane&15)))*448 + (lane>>4)*8;
    short8 a_cur[2];
    a_cur[0] = *(const short8*)(w2base);
    a_cur[1] = *(const short8*)(w2base + 16*448);

    for(int ck=0; ck<14; ck++){
      short8 a_nxt[2];
      if(ck < 13){
        a_nxt[0] = *(const short8*)(w2base + (ck+1)*32);
        a_nxt[1] = *(const short8*)(w2base + 16*448 + (ck+1)*32);
      }
      int r = ck >> 1, i0 = (ck & 1)*32;
      int p = (r+1) & 1;
      int m = ((r-3) - p) >> 1;
      int base = (p?6800:0) + (m+2 + (lane&15))*68 + i0 + (lane>>4)*8;
      short8 b[6];
#pragma unroll
      for(int nt=0;nt<6;nt++)
        b[nt] = *(const short8*)(slabs + base + nt*16*68);
      __builtin_amdgcn_s_setprio(1);
#pragma unroll
      for(int mm=0;mm<2;mm++)
#pragma unroll
        for(int nt=0;nt<6;nt++)
          acc[mm][nt] = __builtin_amdgcn_mfma_f32_16x16x32_bf16(a_cur[mm], b[nt], acc[mm][nt], 0, 0, 0);
      __builtin_amdgcn_s_setprio(0);
      if(ck < 13){ a_cur[0] = a_nxt[0]; a_cur[1] = a_nxt[1]; }
    }

#pragma unroll
    for(int mm=0;mm<2;mm++){
#pragma unroll
      for(int reg=0;reg<4;reg++){
        int o = (w*2+mm)*16 + (lane>>4)*4 + reg;
        float bias = b2[o];
#pragma unroll
        for(int nt=0;nt<6;nt++){
          int tl = nt*16 + (lane&15);
          int t = tbase + tl;
          if(t < L2O){
            float v = acc[mm][nt][reg] + bias;
            v = v>=0.f ? v : 0.2f*v;
            y2buf[((t&1)?11424:0) + ((t>>1)+1)*136 + o] = f2bf(v);
          }
        }
      }
    }
  } // tile loop
  __syncthreads();

  // conv3 phase
  f32x4 acc3[4][5];
#pragma unroll
  for(int i=0;i<4;i++)
#pragma unroll
    for(int j=0;j<5;j++) acc3[i][j] = zero4;

  const unsigned short* wbase = w3p + ((size_t)(w*64) + (lane&15))*1152 + (lane>>4)*8;
  short8 abuf[3][4];
#pragma unroll
  for(int d=0; d<2; d++)
#pragma unroll
    for(int mm=0;mm<4;mm++)
      abuf[d][mm] = *(const short8*)(wbase + mm*16*1152 + d*32);

#pragma unroll
  for(int ck=0; ck<36; ck++){
    const int cur = ck % 3;
    const int nxt = (ck+2) % 3;
    if(ck+2 < 36){
      int kc = (ck+2)*32;
#pragma unroll
      for(int mm=0;mm<4;mm++)
        abuf[nxt][mm] = *(const short8*)(wbase + mm*16*1152 + kc);
    }
    int r = ck >> 2, i0 = (ck & 3) * 32;
    int cbase = ((r & 1) ? 11424 : 0) + (r >> 1)*136 + i0 + (lane>>4)*8;
    short8 b[5];
#pragma unroll
    for(int nt=0;nt<5;nt++){
      int t = nt*16 + (lane&15);
      b[nt] = *(const short8*)(y2buf + cbase + t*136);
    }
    __builtin_amdgcn_s_setprio(1);
#pragma unroll
    for(int mm=0;mm<4;mm++)
#pragma unroll
      for(int nt=0;nt<5;nt++)
        acc3[mm][nt] = __builtin_amdgcn_mfma_f32_16x16x32_bf16(abuf[cur][mm], b[nt], acc3[mm][nt], 0, 0, 0);
    __builtin_amdgcn_s_setprio(0);
  }
#pragma unroll
  for(int mm=0;mm<4;mm++){
#pragma unroll
    for(int reg=0;reg<4;reg++){
      int o = w*64 + mm*16 + (lane>>4)*4 + reg;
      float bias = b3[o];
#pragma unroll
      for(int nt=0;nt<5;nt++){
        int t = nt*16 + (lane&15);
        if(t < L3O){
          float v = acc3[mm][nt][reg] + bias;
          v = v>=0.f ? v : 0.2f*v;
          flatbf[(size_t)n*FLATSZ + o*L3O + t] = f2bf(v);
        }
      }
    }
  }
}

// ---------- split-K MFMA GEMM (r19, unchanged) ----------
__global__ __launch_bounds__(256, 4)
void mb_gemm_mfma(const unsigned short* __restrict__ flatbf, const unsigned short* __restrict__ mbwT,
                  float* __restrict__ part){
  __shared__ unsigned short As[2][4096];   // [64][64] elems, swizzled
  __shared__ unsigned short Bs[2][4096];
  int tid = threadIdx.x;
  int lane = tid & 63, w = tid >> 6;
  int m0 = blockIdx.x*64, n0 = blockIdx.y*64, bz = blockIdx.z;
  int s_start = bz*19 + (bz < 12 ? bz : 12);
  int s_count = 19 + (bz < 12 ? 1 : 0);

  int r0 = tid >> 3,        c80 = tid & 7;
  int r1 = 32 + (tid >> 3), c81 = tid & 7;
  const unsigned short* aptr0 = flatbf + (size_t)(m0+r0)*FLATSZ + c80*8;
  const unsigned short* aptr1 = flatbf + (size_t)(m0+r1)*FLATSZ + c81*8;
  const unsigned short* bptr0 = mbwT  + (size_t)(n0+r0)*FLATSZ + c80*8;
  const unsigned short* bptr1 = mbwT  + (size_t)(n0+r1)*FLATSZ + c81*8;
  int d0 = r0*64 + ((c80 ^ (r0 & 7)) * 8);
  int d1 = r1*64 + ((c81 ^ (r1 & 7)) * 8);

  f32x4 zero = {0.f,0.f,0.f,0.f};
  f32x4 acc[4];
#pragma unroll
  for(int i=0;i<4;i++) acc[i] = zero;

  int arow = w*16 + (lane&15);
  int af0 = arow*64 + ((((lane>>4)  ) ^ (arow & 7)) * 8);
  int af1 = arow*64 + (((4+(lane>>4)) ^ (arow & 7)) * 8);
  int bf0[4], bf1[4];
#pragma unroll
  for(int nt=0;nt<4;nt++){
    int br = nt*16 + (lane&15);
    bf0[nt] = br*64 + ((((lane>>4)  ) ^ (br & 7)) * 8);
    bf1[nt] = br*64 + (((4+(lane>>4)) ^ (br & 7)) * 8);
  }

  size_t koff = (size_t)s_start * 64;
  uint4 ra0 = *(const uint4*)(aptr0 + koff);
  uint4 ra1 = *(const uint4*)(aptr1 + koff);
  uint4 rb0 = *(const uint4*)(bptr0 + koff);
  uint4 rb1 = *(const uint4*)(bptr1 + koff);

  for(int s=0; s<s_count; s++){
    int cur = s & 1;
    *(uint4*)(As[cur] + d0) = ra0;
    *(uint4*)(As[cur] + d1) = ra1;
    *(uint4*)(Bs[cur] + d0) = rb0;
    *(uint4*)(Bs[cur] + d1) = rb1;
    koff += 64;
    if(s+1 < s_count){
      ra0 = *(const uint4*)(aptr0 + koff);
      ra1 = *(const uint4*)(aptr1 + koff);
      rb0 = *(const uint4*)(bptr0 + koff);
      rb1 = *(const uint4*)(bptr1 + koff);
    }
    __syncthreads();
    short8 a0 = *(const short8*)(As[cur] + af0);
    short8 a1 = *(const short8*)(As[cur] + af1);
    short8 b0h0 = *(const short8*)(Bs[cur] + bf0[0]);
    short8 b1h0 = *(const short8*)(Bs[cur] + bf0[1]);
    short8 b2h0 = *(const short8*)(Bs[cur] + bf0[2]);
    short8 b3h0 = *(const short8*)(Bs[cur] + bf0[3]);
    short8 b0h1 = *(const short8*)(Bs[cur] + bf1[0]);
    short8 b1h1 = *(const short8*)(Bs[cur] + bf1[1]);
    short8 b2h1 = *(const short8*)(Bs[cur] + bf1[2]);
    short8 b3h1 = *(const short8*)(Bs[cur] + bf1[3]);
    __builtin_amdgcn_s_setprio(1);
    acc[0] = __builtin_amdgcn_mfma_f32_16x16x32_bf16(a0, b0h0, acc[0], 0, 0, 0);
    acc[1] = __builtin_amdgcn_mfma_f32_16x16x32_bf16(a0, b1h0, acc[1], 0, 0, 0);
    acc[2] = __builtin_amdgcn_mfma_f32_16x16x32_bf16(a0, b2h0, acc[2], 0, 0, 0);
    acc[3] = __builtin_amdgcn_mfma_f32_16x16x32_bf16(a0, b3h0, acc[3], 0, 0, 0);
    acc[0] = __builtin_amdgcn_mfma_f32_16x16x32_bf16(a1, b0h1, acc[0], 0, 0, 0);
    acc[1] = __builtin_amdgcn_mfma_f32_16x16x32_bf16(a1, b1h1, acc[1], 0, 0, 0);
    acc[2] = __builtin_amdgcn_mfma_f32_16x16x32_bf16(a1, b2h1, acc[2], 0, 0, 0);
    acc[3] = __builtin_amdgcn_mfma_f32_16x16x32_bf16(a1, b3h1, acc[3], 0, 0, 0);
    __builtin_amdgcn_s_setprio(0);
  }
  float* po = part + (size_t)bz*NB*500;
#pragma unroll
  for(int nt=0;nt<4;nt++){
#pragma unroll
    for(int reg=0;reg<4;reg++){
      int m = m0 + w*16 + (lane>>4)*4 + reg;
      int c = n0 + nt*16 + (lane&15);
      if(c < 500) po[(size_t)m*500 + c] = acc[nt][reg];
    }
  }
}

// ---------- coop2: mb_reduce -> sync -> feats -> sync -> final ----------
__global__ __launch_bounds__(256)
void coop2_kernel(const float* __restrict__ part, float* __restrict__ actT,
                  float* __restrict__ feats,
                  const unsigned short* __restrict__ flatbf, const int* __restrict__ condition,
                  const float* __restrict__ emb, const float* __restrict__ cond_w,
                  const float* __restrict__ cond_b, const float* __restrict__ fc_w,
                  const float* __restrict__ fc_b, float* __restrict__ out){
  __shared__ float ash[4][50];
  __shared__ float pred[4][4];
  __shared__ float red[4];
  cg::grid_group grid = cg::this_grid();
  int bid = blockIdx.x, tid = threadIdx.x;
  int lane = tid & 63, wv = tid >> 6;

  // ---- phase A: reduce partials -> actT[c][n] ----
  for(int idx = bid*256 + tid; idx < NB*500; idx += COOPG*256){
    float s = 0.f;
#pragma unroll
    for(int z=0;z<SPLITK;z++) s += part[(size_t)z*NB*500 + idx];
    int n = idx/500, c = idx - n*500;
    actT[(size_t)c*NB + n] = s;
  }

  grid.sync();

  // ---- phase B: feats (grid-stride over 128x10 works) ----
  const float LOG2E = 1.4426950408889634f;
  for(int bw = bid; bw < 128*10; bw += COOPG){
    int i0 = (bw & 127)*4, k0 = (bw >> 7)*10;
    if(tid < 200){
      int ii = tid/50, c = tid - ii*50;
      ash[ii][c] = actT[(size_t)(k0*5+c)*NB + i0 + ii];
    }
    __syncthreads();
    int j1 = tid, j2 = tid + 256;
    for(int kk=0; kk<10; kk++){
      const float* r0 = actT + (size_t)(k0+kk)*5*NB;
      float xa0=r0[j1], xa1=r0[NB+j1], xa2=r0[2*NB+j1], xa3=r0[3*NB+j1], xa4=r0[4*NB+j1];
      float xb0=r0[j2], xb1=r0[NB+j2], xb2=r0[2*NB+j2], xb3=r0[3*NB+j2], xb4=r0[4*NB+j2];
      float f[4];
#pragma unroll
      for(int ii=0; ii<4; ii++){
        float a0=ash[ii][kk*5+0], a1=ash[ii][kk*5+1], a2=ash[ii][kk*5+2],
              a3=ash[ii][kk*5+3], a4=ash[ii][kk*5+4];
        float la = fabsf(xa0-a0)+fabsf(xa1-a1)+fabsf(xa2-a2)+fabsf(xa3-a3)+fabsf(xa4-a4);
        float lb = fabsf(xb0-a0)+fabsf(xb1-a1)+fabsf(xb2-a2)+fabsf(xb3-a3)+fabsf(xb4-a4);
        f[ii] = exp2f(-LOG2E*la) + exp2f(-LOG2E*lb);
      }
#pragma unroll
      for(int ii=0; ii<4; ii++){
        float v = f[ii];
#pragma unroll
        for(int s=32; s>0; s>>=1) v += __shfl_down(v, s, 64);
        if(lane==0) pred[wv][ii] = v;
      }
      __syncthreads();
      if(tid < 4){
        float v = pred[0][tid] + pred[1][tid] + pred[2][tid] + pred[3][tid];
        feats[(size_t)(i0+tid)*NUMK + k0 + kk] = v;
      }
      __syncthreads();
    }
  }

  grid.sync();

  // ---- phase C: final (grid-stride over 512 samples) ----
  for(int n = bid; n < NB; n += COOPG){
    float s = 0.f;
    const unsigned short* fr = flatbf + (size_t)n*FLATSZ;
    for(int q=tid; q<FLATSZ/8; q+=256){
      uint4 u = *(const uint4*)(fr + q*8);
      float4 wa = *(const float4*)(fc_w + q*8);
      float4 wb = *(const float4*)(fc_w + q*8 + 4);
      s += bf2f((unsigned short)(u.x & 0xffff))*wa.x + bf2f((unsigned short)(u.x >> 16))*wa.y
         + bf2f((unsigned short)(u.y & 0xffff))*wa.z + bf2f((unsigned short)(u.y >> 16))*wa.w
         + bf2f((unsigned short)(u.z & 0xffff))*wb.x + bf2f((unsigned short)(u.z >> 16))*wb.y
         + bf2f((unsigned short)(u.w & 0xffff))*wb.z + bf2f((unsigned short)(u.w >> 16))*wb.w;
    }
    for(int k=tid;k<NUMK;k+=256) s += feats[n*NUMK+k]*fc_w[FLATSZ+k];
    float ce = emb[condition[n]];
    for(int j=tid;j<50;j+=256) s += (ce*cond_w[j]+cond_b[j])*fc_w[FLATSZ+NUMK+j];
    s = block_reduce_sum(s, red);
    if(tid==0) out[n] = s + fc_b[0];
  }
}

extern "C" void kernel_launch(void* const* d_in, const int* in_sizes, int n_in,
                              void* d_out, int out_size, void* d_ws, size_t ws_size,
                              hipStream_t stream) {
  const float* ecg   = (const float*)d_in[0];
  const int*   cond  = (const int*)  d_in[1];
  const float* w1    = (const float*)d_in[2];
  const float* b1    = (const float*)d_in[3];
  const float* u1    = (const float*)d_in[4];
  const float* w2    = (const float*)d_in[5];
  const float* b2    = (const float*)d_in[6];
  const float* u2    = (const float*)d_in[7];
  const float* w3    = (const float*)d_in[8];
  const float* b3    = (const float*)d_in[9];
  const float* u3    = (const float*)d_in[10];
  const float* emb   = (const float*)d_in[11];
  const float* condw = (const float*)d_in[12];
  const float* condb = (const float*)d_in[13];
  const float* mbw   = (const float*)d_in[14];
  const float* fcw   = (const float*)d_in[15];
  const float* fcb   = (const float*)d_in[16];

  float* ws = (float*)d_ws;
  float* ss_part  = ws + 16;                              // 8 slots
  float* v_all    = ws + 32;                              // ends 1648
  unsigned short* w1p  = (unsigned short*)(ws + 1648);    // -> 2672
  unsigned short* w2p  = (unsigned short*)(ws + 2672);    // -> 31344
  unsigned short* w3p  = (unsigned short*)(ws + 31344);   // -> 178800
  unsigned short* mbwT = (unsigned short*)(ws + 178800);  // 512 rows x 20224 bf16
  float* part  = ws + 5454448;                            // 16*512*500 f -> 9,550,448
  float* Sun_part = part;                                 // 112 slots, dead before gemm writes part
  float* actT  = ws + 9550448;                            // 256,000 f -> 9,806,448
  float* feats = ws + 9806448;                            // 51,200 f -> 9,857,648
  unsigned short* flatbf = (unsigned short*)(ws + 9857648); // 5,177,344 f -> ends 15,034,992

  {
    void* a1[] = {(void*)&w1,(void*)&u1,(void*)&w2,(void*)&u2,(void*)&w3,(void*)&u3,
                  (void*)&v_all,(void*)&ss_part,(void*)&Sun_part,(void*)&mbw,(void*)&mbwT,
                  (void*)&w1p,(void*)&w2p,(void*)&w3p};
    hipLaunchCooperativeKernel((const void*)coop1_kernel, dim3(COOPG), dim3(256), a1, 0, stream);
  }
  conv123_mfma<<<NB, 256, 0, stream>>>(ecg, w1p, b1, w2p, b2, w3p, b3, flatbf);
  mb_gemm_mfma<<<dim3(8,8,SPLITK), 256, 0, stream>>>(flatbf, mbwT, part);
  {
    void* a2[] = {(void*)&part,(void*)&actT,(void*)&feats,(void*)&flatbf,(void*)&cond,
                  (void*)&emb,(void*)&condw,(void*)&condb,(void*)&fcw,(void*)&fcb,
                  (void*)&d_out};
    hipLaunchCooperativeKernel((const void*)coop2_kernel, dim3(COOPG), dim3(256), a2, 0, stream);
  }
}

// Round 11
// 596.475 us; speedup vs baseline: 1.2722x; 1.2722x over previous
//
#include <hip/hip_runtime.h>
#include <math.h>

#define NB 512
#define LIN 640
#define NLEADS 3
#define L1O 322
#define L2O 161
#define L3O 79
#define C1N 64
#define C2N 128
#define C3N 256
#define FLATSZ 20224   // 256*79
#define NUMK 100
#define DIMK 5
#define SPLITK 16

typedef __attribute__((ext_vector_type(8))) short short8;
typedef __attribute__((ext_vector_type(4))) float f32x4;

__device__ __forceinline__ unsigned short f2bf(float x){
  unsigned u = __builtin_bit_cast(unsigned, x);
  unsigned r = u + 0x7FFFu + ((u >> 16) & 1u);
  return (unsigned short)(r >> 16);
}
__device__ __forceinline__ float bf2f(unsigned short x){
  unsigned u = ((unsigned)x) << 16;
  return __builtin_bit_cast(float, u);
}

__device__ __forceinline__ float block_reduce_sum(float val, float* red){
#pragma unroll
  for(int off=32; off>0; off>>=1) val += __shfl_down(val, off, 64);
  int lane = threadIdx.x & 63;
  int wv = threadIdx.x >> 6;
  if(lane==0) red[wv] = val;
  __syncthreads();
  int nw = blockDim.x >> 6;
  float r = red[0];
  for(int i=1;i<nw;i++) r += red[i];
  __syncthreads();
  return r;
}

// ---------- r21: single-block spectral-norm (pass1 + pass2 + scale), replaces
// sn_pass1 + sn_pass2 + sn_final + memset (no atomics -> no pre-zeroing). ~350K MACs
// per pass, ~1.4K/thread — latency-bound ~10us, cheaper than 3 launches + memset.
__global__ __launch_bounds__(256)
void sn_all(const float* __restrict__ w1, const float* __restrict__ u1,
            const float* __restrict__ w2, const float* __restrict__ u2,
            const float* __restrict__ w3, const float* __restrict__ u3,
            float* __restrict__ v_all, float* __restrict__ scale){
  __shared__ float red[4];
  int tid = threadIdx.x, lane = tid & 63, wv = tid >> 6;
  const float* W[3] = {w1,w2,w3};
  const float* U[3] = {u1,u2,u3};
  const int Os[3] = {64,128,256}, Cs[3] = {15,448,1152}, offs[3] = {0,16,464};
#pragma unroll 1
  for(int l=0;l<3;l++){
    const float* w = W[l]; const float* u = U[l];
    int O = Os[l], C = Cs[l], off = offs[l];
    // pass1: v = W^T u (per column), ss = ||v||^2
    float ssacc = 0.f;
    for(int c=tid; c<C; c+=256){
      float vv = 0.f;
      for(int o=0;o<O;o+=4){
        vv += w[(o+0)*C+c]*u[o+0] + w[(o+1)*C+c]*u[o+1]
            + w[(o+2)*C+c]*u[o+2] + w[(o+3)*C+c]*u[o+3];
      }
      v_all[off+c] = vv;
      ssacc += vv*vv;
    }
    float ss = block_reduce_sum(ssacc, red);   // barrier also orders v_all writes
    // pass2: Sun = sum_o (w_row_o . v)^2 ; wave-per-row
    float sunacc = 0.f;
    for(int o=wv; o<O; o+=4){
      float t = 0.f;
      for(int c=lane; c<C; c+=64) t += w[o*C+c]*v_all[off+c];
#pragma unroll
      for(int s=32; s>0; s>>=1) t += __shfl_down(t, s, 64);
      if(lane==0) sunacc += t*t;
    }
    float Sun = block_reduce_sum(sunacc, red);
    if(tid==0){
      float inv = 1.f/(sqrtf(ss)+1e-12f);
      float S = Sun*inv*inv;
      scale[l] = (sqrtf(S)+1e-12f)/S;
    }
    __syncthreads();
  }
}

// ---------- weight prep (original scale-based form) ----------
__global__ void wprep_kernel(const float* __restrict__ w1, const float* __restrict__ w2,
                             const float* __restrict__ w3, const float* __restrict__ scale,
                             unsigned short* __restrict__ w1p, unsigned short* __restrict__ w2p,
                             unsigned short* __restrict__ w3p){
  int idx = blockIdx.x*256 + threadIdx.x;
  float s1 = scale[0], s2 = scale[1], s3 = scale[2];
  if(idx < C1N*32){
    int o = idx >> 5, kk = idx & 31;
    w1p[idx] = (kk < 15) ? f2bf(w1[o*15+kk]*s1) : 0;
  }
  if(idx < C2N*448){
    int o = idx / 448, k2 = idx - o*448;
    int r = k2 >> 6, i = k2 & 63;
    w2p[idx] = f2bf(w2[o*448 + i*7 + r]*s2);
  }
  if(idx < C3N*1152){
    int o = idx / 1152, k2 = idx - o*1152;
    int r = k2 >> 7, i = k2 & 127;
    w3p[idx] = f2bf(w3[o*1152 + i*9 + r]*s3);
  }
}

// ---------- FUSED conv1+conv2+conv3 (r17, unchanged) ----------
__global__ __launch_bounds__(256, 2)
void conv123_mfma(const float* __restrict__ ecg, const unsigned short* __restrict__ w1p,
                  const float* __restrict__ b1, const unsigned short* __restrict__ w2p,
                  const float* __restrict__ b2, const unsigned short* __restrict__ w3p,
                  const float* __restrict__ b3, unsigned short* __restrict__ flatbf){
  __shared__ unsigned short y2buf[22712];   // even slab 84*136 @0; odd slab 83*136 @11424
  __shared__ unsigned short slabs[13600];   // y1 parity slabs (per tile): even [100][68] @0, odd @6800
  __shared__ unsigned short B1s[3328];      // [208][16] u16 — conv1 im2col (kk 0..15; 15=pad)
  int n = blockIdx.x, tid = threadIdx.x;
  int lane = tid & 63, w = tid >> 6;

  if(tid < 136){
    y2buf[tid] = 0;
    y2buf[82*136 + tid] = 0;
    y2buf[83*136 + tid] = 0;
    y2buf[11424 + tid] = 0;
    y2buf[11424 + 81*136 + tid] = 0;
    y2buf[11424 + 82*136 + tid] = 0;
  }

  const float* eb = ecg + (size_t)n*LIN*NLEADS;
  f32x4 zero4 = {0.f,0.f,0.f,0.f};

  for(int tile=0; tile<2; tile++){
    int c0    = tile ? 189 : 0;
    int tbase = tile ? 96  : 0;
    int suboff= tile ? -94 : 2;

    __syncthreads();
    {
      uint4 z = {0u,0u,0u,0u};
      uint4* zd = (uint4*)slabs;
#pragma unroll
      for(int q=0;q<7;q++){
        int f = q*256 + tid;
        if(f < 1700) zd[f] = z;
      }
    }
    if(tid < 208){
      int t1 = c0 + tid;
      int p0 = 2*t1 - 4;
      unsigned short row16[16];
      row16[15] = 0;
      if(p0 >= 0 && p0 <= 635){
        const float* f = eb + p0*NLEADS;
#pragma unroll
        for(int rp=0; rp<5; rp++)
#pragma unroll
          for(int i=0;i<3;i++)
            row16[i*5+rp] = f2bf(f[3*rp+i]);
      } else {
#pragma unroll
        for(int rp=0; rp<5; rp++){
          int p = p0 + rp;
          bool ok = (unsigned)p < (unsigned)LIN;
#pragma unroll
          for(int i=0;i<3;i++)
            row16[i*5+rp] = ok ? f2bf(eb[p*NLEADS+i]) : (unsigned short)0;
        }
      }
      unsigned* dst = (unsigned*)(B1s + tid*16);
#pragma unroll
      for(int q=0;q<8;q++)
        dst[q] = (unsigned)row16[2*q] | ((unsigned)row16[2*q+1] << 16);
    }
    __syncthreads();

    // conv1 MFMA -> y1 parity slabs
    {
      short8 a1 = *(const short8*)(w1p + ((w*16 + (lane&15))<<5) + (lane>>4)*8);
      int cfrag = lane >> 4;
#pragma unroll
      for(int half=0; half<2; half++){
        int nt0 = half*7, ntc = half ? 6 : 7;
        f32x4 c1[7];
        for(int j=0;j<ntc;j++){
          int tp = (nt0+j)*16 + (lane&15);
          short8 b = {0,0,0,0,0,0,0,0};
          if(cfrag < 2) b = *(const short8*)(B1s + tp*16 + cfrag*8);
          c1[j] = __builtin_amdgcn_mfma_f32_16x16x32_bf16(a1, b, zero4, 0, 0, 0);
        }
#pragma unroll
        for(int reg=0;reg<4;reg++){
          int o = w*16 + (lane>>4)*4 + reg;
          float bias = b1[o];
          for(int j=0;j<ntc;j++){
            int tp = (nt0+j)*16 + (lane&15);
            int t1 = c0 + tp;
            int sub = (t1>>1) + suboff;
            if(t1 < L1O && sub < 100){
              float v = c1[j][reg] + bias;
              v = v>=0.f ? v : 0.2f*v;
              slabs[((t1&1)?6800:0) + sub*68 + o] = f2bf(v);
            }
          }
        }
      }
    }
    __syncthreads();

    // conv2 K-loop -> epilogue into y2buf
    f32x4 acc[2][6];
#pragma unroll
    for(int i=0;i<2;i++)
#pragma unroll
      for(int j=0;j<6;j++) acc[i][j] = zero4;

    const unsigned short* w2base = w2p + ((size_t)(w*2*16 + (lane&15)))*448 + (lane>>4)*8;
    short8 a_cur[2];
    a_cur[0] = *(const short8*)(w2base);
    a_cur[1] = *(const short8*)(w2base + 16*448);

    for(int ck=0; ck<14; ck++){
      short8 a_nxt[2];
      if(ck < 13){
        a_nxt[0] = *(const short8*)(w2base + (ck+1)*32);
        a_nxt[1] = *(const short8*)(w2base + 16*448 + (ck+1)*32);
      }
      int r = ck >> 1, i0 = (ck & 1)*32;
      int p = (r+1) & 1;
      int m = ((r-3) - p) >> 1;
      int base = (p?6800:0) + (m+2 + (lane&15))*68 + i0 + (lane>>4)*8;
      short8 b[6];
#pragma unroll
      for(int nt=0;nt<6;nt++)
        b[nt] = *(const short8*)(slabs + base + nt*16*68);
      __builtin_amdgcn_s_setprio(1);
#pragma unroll
      for(int mm=0;mm<2;mm++)
#pragma unroll
        for(int nt=0;nt<6;nt++)
          acc[mm][nt] = __builtin_amdgcn_mfma_f32_16x16x32_bf16(a_cur[mm], b[nt], acc[mm][nt], 0, 0, 0);
      __builtin_amdgcn_s_setprio(0);
      if(ck < 13){ a_cur[0] = a_nxt[0]; a_cur[1] = a_nxt[1]; }
    }

#pragma unroll
    for(int mm=0;mm<2;mm++){
#pragma unroll
      for(int reg=0;reg<4;reg++){
        int o = (w*2+mm)*16 + (lane>>4)*4 + reg;
        float bias = b2[o];
#pragma unroll
        for(int nt=0;nt<6;nt++){
          int tl = nt*16 + (lane&15);
          int t = tbase + tl;
          if(t < L2O){
            float v = acc[mm][nt][reg] + bias;
            v = v>=0.f ? v : 0.2f*v;
            y2buf[((t&1)?11424:0) + ((t>>1)+1)*136 + o] = f2bf(v);
          }
        }
      }
    }
  } // tile loop
  __syncthreads();

  // conv3 phase
  f32x4 acc3[4][5];
#pragma unroll
  for(int i=0;i<4;i++)
#pragma unroll
    for(int j=0;j<5;j++) acc3[i][j] = zero4;

  const unsigned short* wbase = w3p + ((size_t)(w*64) + (lane&15))*1152 + (lane>>4)*8;
  short8 abuf[3][4];
#pragma unroll
  for(int d=0; d<2; d++)
#pragma unroll
    for(int mm=0;mm<4;mm++)
      abuf[d][mm] = *(const short8*)(wbase + mm*16*1152 + d*32);

#pragma unroll
  for(int ck=0; ck<36; ck++){
    const int cur = ck % 3;
    const int nxt = (ck+2) % 3;
    if(ck+2 < 36){
      int kc = (ck+2)*32;
#pragma unroll
      for(int mm=0;mm<4;mm++)
        abuf[nxt][mm] = *(const short8*)(wbase + mm*16*1152 + kc);
    }
    int r = ck >> 2, i0 = (ck & 3) * 32;
    int cbase = ((r & 1) ? 11424 : 0) + (r >> 1)*136 + i0 + (lane>>4)*8;
    short8 b[5];
#pragma unroll
    for(int nt=0;nt<5;nt++){
      int t = nt*16 + (lane&15);
      b[nt] = *(const short8*)(y2buf + cbase + t*136);
    }
    __builtin_amdgcn_s_setprio(1);
#pragma unroll
    for(int mm=0;mm<4;mm++)
#pragma unroll
      for(int nt=0;nt<5;nt++)
        acc3[mm][nt] = __builtin_amdgcn_mfma_f32_16x16x32_bf16(abuf[cur][mm], b[nt], acc3[mm][nt], 0, 0, 0);
    __builtin_amdgcn_s_setprio(0);
  }
#pragma unroll
  for(int mm=0;mm<4;mm++){
#pragma unroll
    for(int reg=0;reg<4;reg++){
      int o = w*64 + mm*16 + (lane>>4)*4 + reg;
      float bias = b3[o];
#pragma unroll
      for(int nt=0;nt<5;nt++){
        int t = nt*16 + (lane&15);
        if(t < L3O){
          float v = acc3[mm][nt][reg] + bias;
          v = v>=0.f ? v : 0.2f*v;
          flatbf[(size_t)n*FLATSZ + o*L3O + t] = f2bf(v);
        }
      }
    }
  }
}

// ---------- transpose + bf16: mbwT[n][k] ----------
__global__ __launch_bounds__(256)
void mbw_transpose(const float* __restrict__ mbw, unsigned short* __restrict__ mbwT){
  __shared__ unsigned short tile[32][36];
  int k0 = blockIdx.x*32, n0 = blockIdx.y*32, tid = threadIdx.x;
  int r = tid >> 3, c4 = (tid & 7) * 4;
  int nbase = n0 + c4;
  if(nbase + 3 < 500){
    float4 v = *(const float4*)(mbw + (size_t)(k0+r)*500 + nbase);
    tile[r][c4+0] = f2bf(v.x);
    tile[r][c4+1] = f2bf(v.y);
    tile[r][c4+2] = f2bf(v.z);
    tile[r][c4+3] = f2bf(v.w);
  } else {
#pragma unroll
    for(int j=0;j<4;j++){
      int nn = nbase + j;
      float v = (nn < 500) ? mbw[(size_t)(k0+r)*500 + nn] : 0.f;
      tile[r][c4+j] = f2bf(v);
    }
  }
  __syncthreads();
  int nl = tid >> 3, kq = (tid & 7) * 4;
  unsigned short t0 = tile[kq+0][nl], t1 = tile[kq+1][nl];
  unsigned short t2 = tile[kq+2][nl], t3 = tile[kq+3][nl];
  uint2 p;
  p.x = (unsigned)t0 | ((unsigned)t1 << 16);
  p.y = (unsigned)t2 | ((unsigned)t3 << 16);
  *(uint2*)(mbwT + (size_t)(n0+nl)*FLATSZ + k0 + kq) = p;
}

// ---------- split-K MFMA GEMM (r19, unchanged) ----------
__global__ __launch_bounds__(256, 4)
void mb_gemm_mfma(const unsigned short* __restrict__ flatbf, const unsigned short* __restrict__ mbwT,
                  float* __restrict__ part){
  __shared__ unsigned short As[2][4096];   // [64][64] elems, swizzled
  __shared__ unsigned short Bs[2][4096];
  int tid = threadIdx.x;
  int lane = tid & 63, w = tid >> 6;
  int m0 = blockIdx.x*64, n0 = blockIdx.y*64, bz = blockIdx.z;
  int s_start = bz*19 + (bz < 12 ? bz : 12);
  int s_count = 19 + (bz < 12 ? 1 : 0);

  int r0 = tid >> 3,        c80 = tid & 7;
  int r1 = 32 + (tid >> 3), c81 = tid & 7;
  const unsigned short* aptr0 = flatbf + (size_t)(m0+r0)*FLATSZ + c80*8;
  const unsigned short* aptr1 = flatbf + (size_t)(m0+r1)*FLATSZ + c81*8;
  const unsigned short* bptr0 = mbwT  + (size_t)(n0+r0)*FLATSZ + c80*8;
  const unsigned short* bptr1 = mbwT  + (size_t)(n0+r1)*FLATSZ + c81*8;
  int d0 = r0*64 + ((c80 ^ (r0 & 7)) * 8);
  int d1 = r1*64 + ((c81 ^ (r1 & 7)) * 8);

  f32x4 zero = {0.f,0.f,0.f,0.f};
  f32x4 acc[4];
#pragma unroll
  for(int i=0;i<4;i++) acc[i] = zero;

  int arow = w*16 + (lane&15);
  int af0 = arow*64 + ((((lane>>4)  ) ^ (arow & 7)) * 8);
  int af1 = arow*64 + (((4+(lane>>4)) ^ (arow & 7)) * 8);
  int bf0[4], bf1[4];
#pragma unroll
  for(int nt=0;nt<4;nt++){
    int br = nt*16 + (lane&15);
    bf0[nt] = br*64 + ((((lane>>4)  ) ^ (br & 7)) * 8);
    bf1[nt] = br*64 + (((4+(lane>>4)) ^ (br & 7)) * 8);
  }

  size_t koff = (size_t)s_start * 64;
  uint4 ra0 = *(const uint4*)(aptr0 + koff);
  uint4 ra1 = *(const uint4*)(aptr1 + koff);
  uint4 rb0 = *(const uint4*)(bptr0 + koff);
  uint4 rb1 = *(const uint4*)(bptr1 + koff);

  for(int s=0; s<s_count; s++){
    int cur = s & 1;
    *(uint4*)(As[cur] + d0) = ra0;
    *(uint4*)(As[cur] + d1) = ra1;
    *(uint4*)(Bs[cur] + d0) = rb0;
    *(uint4*)(Bs[cur] + d1) = rb1;
    koff += 64;
    if(s+1 < s_count){
      ra0 = *(const uint4*)(aptr0 + koff);
      ra1 = *(const uint4*)(aptr1 + koff);
      rb0 = *(const uint4*)(bptr0 + koff);
      rb1 = *(const uint4*)(bptr1 + koff);
    }
    __syncthreads();
    short8 a0 = *(const short8*)(As[cur] + af0);
    short8 a1 = *(const short8*)(As[cur] + af1);
    short8 b0h0 = *(const short8*)(Bs[cur] + bf0[0]);
    short8 b1h0 = *(const short8*)(Bs[cur] + bf0[1]);
    short8 b2h0 = *(const short8*)(Bs[cur] + bf0[2]);
    short8 b3h0 = *(const short8*)(Bs[cur] + bf0[3]);
    short8 b0h1 = *(const short8*)(Bs[cur] + bf1[0]);
    short8 b1h1 = *(const short8*)(Bs[cur] + bf1[1]);
    short8 b2h1 = *(const short8*)(Bs[cur] + bf1[2]);
    short8 b3h1 = *(const short8*)(Bs[cur] + bf1[3]);
    __builtin_amdgcn_s_setprio(1);
    acc[0] = __builtin_amdgcn_mfma_f32_16x16x32_bf16(a0, b0h0, acc[0], 0, 0, 0);
    acc[1] = __builtin_amdgcn_mfma_f32_16x16x32_bf16(a0, b1h0, acc[1], 0, 0, 0);
    acc[2] = __builtin_amdgcn_mfma_f32_16x16x32_bf16(a0, b2h0, acc[2], 0, 0, 0);
    acc[3] = __builtin_amdgcn_mfma_f32_16x16x32_bf16(a0, b3h0, acc[3], 0, 0, 0);
    acc[0] = __builtin_amdgcn_mfma_f32_16x16x32_bf16(a1, b0h1, acc[0], 0, 0, 0);
    acc[1] = __builtin_amdgcn_mfma_f32_16x16x32_bf16(a1, b1h1, acc[1], 0, 0, 0);
    acc[2] = __builtin_amdgcn_mfma_f32_16x16x32_bf16(a1, b2h1, acc[2], 0, 0, 0);
    acc[3] = __builtin_amdgcn_mfma_f32_16x16x32_bf16(a1, b3h1, acc[3], 0, 0, 0);
    __builtin_amdgcn_s_setprio(0);
  }
  float* po = part + (size_t)bz*NB*500;
#pragma unroll
  for(int nt=0;nt<4;nt++){
#pragma unroll
    for(int reg=0;reg<4;reg++){
      int m = m0 + w*16 + (lane>>4)*4 + reg;
      int c = n0 + nt*16 + (lane&15);
      if(c < 500) po[(size_t)m*500 + c] = acc[nt][reg];
    }
  }
}

// ---------- reduce partials -> actT[c][n] ----------
__global__ void mb_reduce_kernel(const float* __restrict__ part, float* __restrict__ actT){
  int idx = blockIdx.x*256 + threadIdx.x;   // n*500+c
  float s = 0.f;
#pragma unroll
  for(int z=0;z<SPLITK;z++) s += part[(size_t)z*NB*500 + idx];
  int n = idx/500, c = idx - n*500;
  actT[(size_t)c*NB + n] = s;
}

// ---------- minibatch features ----------
__global__ __launch_bounds__(256)
void feats_kernel(const float* __restrict__ actT, float* __restrict__ feats){
  __shared__ float ash[4][50];
  __shared__ float pred[4][4];
  int i0 = blockIdx.x*4, k0 = blockIdx.y*10;
  int tid = threadIdx.x, lane = tid & 63, wv = tid >> 6;
  if(tid < 200){
    int ii = tid/50, c = tid - ii*50;
    ash[ii][c] = actT[(size_t)(k0*5+c)*NB + i0 + ii];
  }
  __syncthreads();
  const float LOG2E = 1.4426950408889634f;
  int j1 = tid, j2 = tid + 256;
  for(int kk=0; kk<10; kk++){
    const float* r0 = actT + (size_t)(k0+kk)*5*NB;
    float xa0=r0[j1], xa1=r0[NB+j1], xa2=r0[2*NB+j1], xa3=r0[3*NB+j1], xa4=r0[4*NB+j1];
    float xb0=r0[j2], xb1=r0[NB+j2], xb2=r0[2*NB+j2], xb3=r0[3*NB+j2], xb4=r0[4*NB+j2];
    float f[4];
#pragma unroll
    for(int ii=0; ii<4; ii++){
      float a0=ash[ii][kk*5+0], a1=ash[ii][kk*5+1], a2=ash[ii][kk*5+2],
            a3=ash[ii][kk*5+3], a4=ash[ii][kk*5+4];
      float la = fabsf(xa0-a0)+fabsf(xa1-a1)+fabsf(xa2-a2)+fabsf(xa3-a3)+fabsf(xa4-a4);
      float lb = fabsf(xb0-a0)+fabsf(xb1-a1)+fabsf(xb2-a2)+fabsf(xb3-a3)+fabsf(xb4-a4);
      f[ii] = exp2f(-LOG2E*la) + exp2f(-LOG2E*lb);
    }
#pragma unroll
    for(int ii=0; ii<4; ii++){
      float v = f[ii];
#pragma unroll
      for(int s=32; s>0; s>>=1) v += __shfl_down(v, s, 64);
      if(lane==0) pred[wv][ii] = v;
    }
    __syncthreads();
    if(tid < 4){
      float v = pred[0][tid] + pred[1][tid] + pred[2][tid] + pred[3][tid];
      feats[(size_t)(i0+tid)*NUMK + k0 + kk] = v;
    }
    __syncthreads();
  }
}

// ---------- final ----------
__global__ void final_kernel(const unsigned short* __restrict__ flatbf, const float* __restrict__ feats,
                             const int* __restrict__ condition, const float* __restrict__ emb,
                             const float* __restrict__ cond_w, const float* __restrict__ cond_b,
                             const float* __restrict__ fc_w, const float* __restrict__ fc_b,
                             float* __restrict__ out){
  __shared__ float red[4];
  int n = blockIdx.x, tid = threadIdx.x;
  float s = 0.f;
  const unsigned short* fr = flatbf + (size_t)n*FLATSZ;
  for(int q=tid; q<FLATSZ/8; q+=256){
    uint4 u = *(const uint4*)(fr + q*8);
    float4 wa = *(const float4*)(fc_w + q*8);
    float4 wb = *(const float4*)(fc_w + q*8 + 4);
    s += bf2f((unsigned short)(u.x & 0xffff))*wa.x + bf2f((unsigned short)(u.x >> 16))*wa.y
       + bf2f((unsigned short)(u.y & 0xffff))*wa.z + bf2f((unsigned short)(u.y >> 16))*wa.w
       + bf2f((unsigned short)(u.z & 0xffff))*wb.x + bf2f((unsigned short)(u.z >> 16))*wb.y
       + bf2f((unsigned short)(u.w & 0xffff))*wb.z + bf2f((unsigned short)(u.w >> 16))*wb.w;
  }
  for(int k=tid;k<NUMK;k+=256) s += feats[n*NUMK+k]*fc_w[FLATSZ+k];
  float ce = emb[condition[n]];
  for(int j=tid;j<50;j+=256) s += (ce*cond_w[j]+cond_b[j])*fc_w[FLATSZ+NUMK+j];
  s = block_reduce_sum(s, red);
  if(tid==0) out[n] = s + fc_b[0];
}

extern "C" void kernel_launch(void* const* d_in, const int* in_sizes, int n_in,
                              void* d_out, int out_size, void* d_ws, size_t ws_size,
                              hipStream_t stream) {
  const float* ecg   = (const float*)d_in[0];
  const int*   cond  = (const int*)  d_in[1];
  const float* w1    = (const float*)d_in[2];
  const float* b1    = (const float*)d_in[3];
  const float* u1    = (const float*)d_in[4];
  const float* w2    = (const float*)d_in[5];
  const float* b2    = (const float*)d_in[6];
  const float* u2    = (const float*)d_in[7];
  const float* w3    = (const float*)d_in[8];
  const float* b3    = (const float*)d_in[9];
  const float* u3    = (const float*)d_in[10];
  const float* emb   = (const float*)d_in[11];
  const float* condw = (const float*)d_in[12];
  const float* condb = (const float*)d_in[13];
  const float* mbw   = (const float*)d_in[14];
  const float* fcw   = (const float*)d_in[15];
  const float* fcb   = (const float*)d_in[16];

  float* ws = (float*)d_ws;
  float* scale = ws;                                      // 0..16
  float* v_all = ws + 32;                                 // ends 1648
  unsigned short* w1p  = (unsigned short*)(ws + 1648);    // -> 2672
  unsigned short* w2p  = (unsigned short*)(ws + 2672);    // -> 31344
  unsigned short* w3p  = (unsigned short*)(ws + 31344);   // -> 178800
  unsigned short* mbwT = (unsigned short*)(ws + 178800);  // 512 rows x 20224 bf16
  float* part  = ws + 5454448;                            // 16*512*500 f -> 9,550,448
  float* actT  = ws + 9550448;                            // 256,000 f -> 9,806,448
  float* feats = ws + 9806448;                            // 51,200 f -> 9,857,648
  unsigned short* flatbf = (unsigned short*)(ws + 9857648); // 5,177,344 f -> ends 15,034,992

  sn_all<<<1, 256, 0, stream>>>(w1,u1,w2,u2,w3,u3, v_all, scale);
  wprep_kernel<<<1152, 256, 0, stream>>>(w1, w2, w3, scale, w1p, w2p, w3p);
  conv123_mfma<<<NB, 256, 0, stream>>>(ecg, w1p, b1, w2p, b2, w3p, b3, flatbf);
  mbw_transpose<<<dim3(632,16), 256, 0, stream>>>(mbw, mbwT);
  mb_gemm_mfma<<<dim3(8,8,SPLITK), 256, 0, stream>>>(flatbf, mbwT, part);
  mb_reduce_kernel<<<1000, 256, 0, stream>>>(part, actT);
  feats_kernel<<<dim3(128,10), 256, 0, stream>>>(actT, feats);
  final_kernel<<<NB, 256, 0, stream>>>(flatbf, feats, cond, emb, condw, condb, fcw, fcb, (float*)d_out);
}

// Round 12
// 299.074 us; speedup vs baseline: 2.5373x; 1.9944x over previous
//
#include <hip/hip_runtime.h>
#include <math.h>

#define NB 512
#define LIN 640
#define NLEADS 3
#define L1O 322
#define L2O 161
#define L3O 79
#define C1N 64
#define C2N 128
#define C3N 256
#define FLATSZ 20224   // 256*79
#define NUMK 100
#define DIMK 5
#define SPLITK 16

typedef __attribute__((ext_vector_type(8))) short short8;
typedef __attribute__((ext_vector_type(4))) float f32x4;

__device__ __forceinline__ unsigned short f2bf(float x){
  unsigned u = __builtin_bit_cast(unsigned, x);
  unsigned r = u + 0x7FFFu + ((u >> 16) & 1u);
  return (unsigned short)(r >> 16);
}
__device__ __forceinline__ float bf2f(unsigned short x){
  unsigned u = ((unsigned)x) << 16;
  return __builtin_bit_cast(float, u);
}

__device__ __forceinline__ float block_reduce_sum(float val, float* red){
#pragma unroll
  for(int off=32; off>0; off>>=1) val += __shfl_down(val, off, 64);
  int lane = threadIdx.x & 63;
  int wv = threadIdx.x >> 6;
  if(lane==0) red[wv] = val;
  __syncthreads();
  int nw = blockDim.x >> 6;
  float r = red[0];
  for(int i=1;i<nw;i++) r += red[i];
  __syncthreads();
  return r;
}

// ---------- SN pass 1 ----------
__global__ __launch_bounds__(256)
void sn_pass1(const float* __restrict__ w1, const float* __restrict__ u1,
              const float* __restrict__ w2, const float* __restrict__ u2,
              const float* __restrict__ w3, const float* __restrict__ u3,
              float* __restrict__ v_all, float* __restrict__ ss){
  __shared__ float red[4];
  int b = blockIdx.x, tid = threadIdx.x;
  const float* w; const float* u; int O, C, off, c, widx;
  if(b==0){ w=w1; u=u1; O=64;  C=15;   off=0;   c=tid;            widx=0; }
  else if(b<3){ w=w2; u=u2; O=128; C=448; off=16;  c=(b-1)*256+tid; widx=1; }
  else { w=w3; u=u3; O=256; C=1152; off=464; c=(b-3)*256+tid;      widx=2; }
  float vv = 0.f;
  if(c < C){
    for(int o=0;o<O;o+=4){
      vv += w[(o+0)*C+c]*u[o+0] + w[(o+1)*C+c]*u[o+1]
          + w[(o+2)*C+c]*u[o+2] + w[(o+3)*C+c]*u[o+3];
    }
    v_all[off + c] = vv;
  }
  float ps = (c < C) ? vv*vv : 0.f;
  float tot = block_reduce_sum(ps, red);
  if(tid==0) atomicAdd(&ss[widx], tot);
}

// ---------- SN pass 2 ----------
__global__ __launch_bounds__(256)
void sn_pass2(const float* __restrict__ w1, const float* __restrict__ w2,
              const float* __restrict__ w3, const float* __restrict__ v_all,
              float* __restrict__ Sun){
  int b = blockIdx.x, tid = threadIdx.x;
  int lane = tid & 63, wv = tid >> 6;
  const float* w; int C, off, o, widx;
  if(b < 16){ w=w1; C=15;   off=0;   o=b*4+wv;      widx=0; }
  else if(b < 48){ w=w2; C=448; off=16;  o=(b-16)*4+wv; widx=1; }
  else { w=w3; C=1152; off=464; o=(b-48)*4+wv;          widx=2; }
  float t = 0.f;
  for(int c=lane; c<C; c+=64) t += w[o*C+c]*v_all[off+c];
#pragma unroll
  for(int s=32; s>0; s>>=1) t += __shfl_down(t, s, 64);
  if(lane==0) atomicAdd(&Sun[widx], t*t);
}

__global__ void sn_final(const float* __restrict__ ss, const float* __restrict__ Sun,
                         float* __restrict__ scale){
  int tid = threadIdx.x;
  if(tid < 3){
    float inv = 1.f/(sqrtf(ss[tid])+1e-12f);
    float S = Sun[tid]*inv*inv;
    scale[tid] = (sqrtf(S)+1e-12f)/S;
  }
}

// ---------- weight prep: w1 padded; w2 K-PERMUTED (k'=r*64+i); w3 K-PERMUTED (k'=r*128+i) ----------
__global__ void wprep_kernel(const float* __restrict__ w1, const float* __restrict__ w2,
                             const float* __restrict__ w3, const float* __restrict__ scale,
                             unsigned short* __restrict__ w1p, unsigned short* __restrict__ w2p,
                             unsigned short* __restrict__ w3p){
  int idx = blockIdx.x*256 + threadIdx.x;
  float s1 = scale[0], s2 = scale[1], s3 = scale[2];
  if(idx < C1N*32){
    int o = idx >> 5, kk = idx & 31;
    w1p[idx] = (kk < 15) ? f2bf(w1[o*15+kk]*s1) : 0;
  }
  if(idx < C2N*448){
    int o = idx / 448, k2 = idx - o*448;
    int r = k2 >> 6, i = k2 & 63;
    w2p[idx] = f2bf(w2[o*448 + i*7 + r]*s2);
  }
  if(idx < C3N*1152){
    int o = idx / 1152, k2 = idx - o*1152;
    int r = k2 >> 7, i = k2 & 127;
    w3p[idx] = f2bf(w3[o*1152 + i*9 + r]*s3);
  }
}

// ---------- FUSED conv1+conv2+conv3 (r17, unchanged) ----------
__global__ __launch_bounds__(256, 2)
void conv123_mfma(const float* __restrict__ ecg, const unsigned short* __restrict__ w1p,
                  const float* __restrict__ b1, const unsigned short* __restrict__ w2p,
                  const float* __restrict__ b2, const unsigned short* __restrict__ w3p,
                  const float* __restrict__ b3, unsigned short* __restrict__ flatbf){
  __shared__ unsigned short y2buf[22712];   // even slab 84*136 @0; odd slab 83*136 @11424
  __shared__ unsigned short slabs[13600];   // y1 parity slabs (per tile): even [100][68] @0, odd @6800
  __shared__ unsigned short B1s[3328];      // [208][16] u16 — conv1 im2col (kk 0..15; 15=pad)
  int n = blockIdx.x, tid = threadIdx.x;
  int lane = tid & 63, w = tid >> 6;

  if(tid < 136){
    y2buf[tid] = 0;
    y2buf[82*136 + tid] = 0;
    y2buf[83*136 + tid] = 0;
    y2buf[11424 + tid] = 0;
    y2buf[11424 + 81*136 + tid] = 0;
    y2buf[11424 + 82*136 + tid] = 0;
  }

  const float* eb = ecg + (size_t)n*LIN*NLEADS;
  f32x4 zero4 = {0.f,0.f,0.f,0.f};

  for(int tile=0; tile<2; tile++){
    int c0    = tile ? 189 : 0;
    int tbase = tile ? 96  : 0;
    int suboff= tile ? -94 : 2;

    __syncthreads();
    {
      uint4 z = {0u,0u,0u,0u};
      uint4* zd = (uint4*)slabs;
#pragma unroll
      for(int q=0;q<7;q++){
        int f = q*256 + tid;
        if(f < 1700) zd[f] = z;
      }
    }
    if(tid < 208){
      int t1 = c0 + tid;
      int p0 = 2*t1 - 4;
      unsigned short row16[16];
      row16[15] = 0;
      if(p0 >= 0 && p0 <= 635){
        const float* f = eb + p0*NLEADS;
#pragma unroll
        for(int rp=0; rp<5; rp++)
#pragma unroll
          for(int i=0;i<3;i++)
            row16[i*5+rp] = f2bf(f[3*rp+i]);
      } else {
#pragma unroll
        for(int rp=0; rp<5; rp++){
          int p = p0 + rp;
          bool ok = (unsigned)p < (unsigned)LIN;
#pragma unroll
          for(int i=0;i<3;i++)
            row16[i*5+rp] = ok ? f2bf(eb[p*NLEADS+i]) : (unsigned short)0;
        }
      }
      unsigned* dst = (unsigned*)(B1s + tid*16);
#pragma unroll
      for(int q=0;q<8;q++)
        dst[q] = (unsigned)row16[2*q] | ((unsigned)row16[2*q+1] << 16);
    }
    __syncthreads();

    // conv1 MFMA -> y1 parity slabs
    {
      short8 a1 = *(const short8*)(w1p + ((w*16 + (lane&15))<<5) + (lane>>4)*8);
      int cfrag = lane >> 4;
#pragma unroll
      for(int half=0; half<2; half++){
        int nt0 = half*7, ntc = half ? 6 : 7;
        f32x4 c1[7];
        for(int j=0;j<ntc;j++){
          int tp = (nt0+j)*16 + (lane&15);
          short8 b = {0,0,0,0,0,0,0,0};
          if(cfrag < 2) b = *(const short8*)(B1s + tp*16 + cfrag*8);
          c1[j] = __builtin_amdgcn_mfma_f32_16x16x32_bf16(a1, b, zero4, 0, 0, 0);
        }
#pragma unroll
        for(int reg=0;reg<4;reg++){
          int o = w*16 + (lane>>4)*4 + reg;
          float bias = b1[o];
          for(int j=0;j<ntc;j++){
            int tp = (nt0+j)*16 + (lane&15);
            int t1 = c0 + tp;
            int sub = (t1>>1) + suboff;
            if(t1 < L1O && sub < 100){
              float v = c1[j][reg] + bias;
              v = v>=0.f ? v : 0.2f*v;
              slabs[((t1&1)?6800:0) + sub*68 + o] = f2bf(v);
            }
          }
        }
      }
    }
    __syncthreads();

    // conv2 K-loop -> epilogue into y2buf
    f32x4 acc[2][6];
#pragma unroll
    for(int i=0;i<2;i++)
#pragma unroll
      for(int j=0;j<6;j++) acc[i][j] = zero4;

    const unsigned short* w2base = w2p + ((size_t)(w*2*16 + (lane&15)))*448 + (lane>>4)*8;
    short8 a_cur[2];
    a_cur[0] = *(const short8*)(w2base);
    a_cur[1] = *(const short8*)(w2base + 16*448);

    for(int ck=0; ck<14; ck++){
      short8 a_nxt[2];
      if(ck < 13){
        a_nxt[0] = *(const short8*)(w2base + (ck+1)*32);
        a_nxt[1] = *(const short8*)(w2base + 16*448 + (ck+1)*32);
      }
      int r = ck >> 1, i0 = (ck & 1)*32;
      int p = (r+1) & 1;
      int m = ((r-3) - p) >> 1;
      int base = (p?6800:0) + (m+2 + (lane&15))*68 + i0 + (lane>>4)*8;
      short8 b[6];
#pragma unroll
      for(int nt=0;nt<6;nt++)
        b[nt] = *(const short8*)(slabs + base + nt*16*68);
      __builtin_amdgcn_s_setprio(1);
#pragma unroll
      for(int mm=0;mm<2;mm++)
#pragma unroll
        for(int nt=0;nt<6;nt++)
          acc[mm][nt] = __builtin_amdgcn_mfma_f32_16x16x32_bf16(a_cur[mm], b[nt], acc[mm][nt], 0, 0, 0);
      __builtin_amdgcn_s_setprio(0);
      if(ck < 13){ a_cur[0] = a_nxt[0]; a_cur[1] = a_nxt[1]; }
    }

#pragma unroll
    for(int mm=0;mm<2;mm++){
#pragma unroll
      for(int reg=0;reg<4;reg++){
        int o = (w*2+mm)*16 + (lane>>4)*4 + reg;
        float bias = b2[o];
#pragma unroll
        for(int nt=0;nt<6;nt++){
          int tl = nt*16 + (lane&15);
          int t = tbase + tl;
          if(t < L2O){
            float v = acc[mm][nt][reg] + bias;
            v = v>=0.f ? v : 0.2f*v;
            y2buf[((t&1)?11424:0) + ((t>>1)+1)*136 + o] = f2bf(v);
          }
        }
      }
    }
  } // tile loop
  __syncthreads();

  // conv3 phase
  f32x4 acc3[4][5];
#pragma unroll
  for(int i=0;i<4;i++)
#pragma unroll
    for(int j=0;j<5;j++) acc3[i][j] = zero4;

  const unsigned short* wbase = w3p + ((size_t)(w*64) + (lane&15))*1152 + (lane>>4)*8;
  short8 abuf[3][4];
#pragma unroll
  for(int d=0; d<2; d++)
#pragma unroll
    for(int mm=0;mm<4;mm++)
      abuf[d][mm] = *(const short8*)(wbase + mm*16*1152 + d*32);

#pragma unroll
  for(int ck=0; ck<36; ck++){
    const int cur = ck % 3;
    const int nxt = (ck+2) % 3;
    if(ck+2 < 36){
      int kc = (ck+2)*32;
#pragma unroll
      for(int mm=0;mm<4;mm++)
        abuf[nxt][mm] = *(const short8*)(wbase + mm*16*1152 + kc);
    }
    int r = ck >> 2, i0 = (ck & 3) * 32;
    int cbase = ((r & 1) ? 11424 : 0) + (r >> 1)*136 + i0 + (lane>>4)*8;
    short8 b[5];
#pragma unroll
    for(int nt=0;nt<5;nt++){
      int t = nt*16 + (lane&15);
      b[nt] = *(const short8*)(y2buf + cbase + t*136);
    }
    __builtin_amdgcn_s_setprio(1);
#pragma unroll
    for(int mm=0;mm<4;mm++)
#pragma unroll
      for(int nt=0;nt<5;nt++)
        acc3[mm][nt] = __builtin_amdgcn_mfma_f32_16x16x32_bf16(abuf[cur][mm], b[nt], acc3[mm][nt], 0, 0, 0);
    __builtin_amdgcn_s_setprio(0);
  }
#pragma unroll
  for(int mm=0;mm<4;mm++){
#pragma unroll
    for(int reg=0;reg<4;reg++){
      int o = w*64 + mm*16 + (lane>>4)*4 + reg;
      float bias = b3[o];
#pragma unroll
      for(int nt=0;nt<5;nt++){
        int t = nt*16 + (lane&15);
        if(t < L3O){
          float v = acc3[mm][nt][reg] + bias;
          v = v>=0.f ? v : 0.2f*v;
          flatbf[(size_t)n*FLATSZ + o*L3O + t] = f2bf(v);
        }
      }
    }
  }
}

// ---------- transpose + bf16: mbwT[n][k] ----------
__global__ __launch_bounds__(256)
void mbw_transpose(const float* __restrict__ mbw, unsigned short* __restrict__ mbwT){
  __shared__ unsigned short tile[32][36];
  int k0 = blockIdx.x*32, n0 = blockIdx.y*32, tid = threadIdx.x;
  int r = tid >> 3, c4 = (tid & 7) * 4;
  int nbase = n0 + c4;
  if(nbase + 3 < 500){
    float4 v = *(const float4*)(mbw + (size_t)(k0+r)*500 + nbase);
    tile[r][c4+0] = f2bf(v.x);
    tile[r][c4+1] = f2bf(v.y);
    tile[r][c4+2] = f2bf(v.z);
    tile[r][c4+3] = f2bf(v.w);
  } else {
#pragma unroll
    for(int j=0;j<4;j++){
      int nn = nbase + j;
      float v = (nn < 500) ? mbw[(size_t)(k0+r)*500 + nn] : 0.f;
      tile[r][c4+j] = f2bf(v);
    }
  }
  __syncthreads();
  int nl = tid >> 3, kq = (tid & 7) * 4;
  unsigned short t0 = tile[kq+0][nl], t1 = tile[kq+1][nl];
  unsigned short t2 = tile[kq+2][nl], t3 = tile[kq+3][nl];
  uint2 p;
  p.x = (unsigned)t0 | ((unsigned)t1 << 16);
  p.y = (unsigned)t2 | ((unsigned)t3 << 16);
  *(uint2*)(mbwT + (size_t)(n0+nl)*FLATSZ + k0 + kq) = p;
}

// ---------- split-K MFMA GEMM (r19, unchanged) ----------
__global__ __launch_bounds__(256, 4)
void mb_gemm_mfma(const unsigned short* __restrict__ flatbf, const unsigned short* __restrict__ mbwT,
                  float* __restrict__ part){
  __shared__ unsigned short As[2][4096];   // [64][64] elems, swizzled
  __shared__ unsigned short Bs[2][4096];
  int tid = threadIdx.x;
  int lane = tid & 63, w = tid >> 6;
  int m0 = blockIdx.x*64, n0 = blockIdx.y*64, bz = blockIdx.z;
  int s_start = bz*19 + (bz < 12 ? bz : 12);
  int s_count = 19 + (bz < 12 ? 1 : 0);

  int r0 = tid >> 3,        c80 = tid & 7;
  int r1 = 32 + (tid >> 3), c81 = tid & 7;
  const unsigned short* aptr0 = flatbf + (size_t)(m0+r0)*FLATSZ + c80*8;
  const unsigned short* aptr1 = flatbf + (size_t)(m0+r1)*FLATSZ + c81*8;
  const unsigned short* bptr0 = mbwT  + (size_t)(n0+r0)*FLATSZ + c80*8;
  const unsigned short* bptr1 = mbwT  + (size_t)(n0+r1)*FLATSZ + c81*8;
  int d0 = r0*64 + ((c80 ^ (r0 & 7)) * 8);
  int d1 = r1*64 + ((c81 ^ (r1 & 7)) * 8);

  f32x4 zero = {0.f,0.f,0.f,0.f};
  f32x4 acc[4];
#pragma unroll
  for(int i=0;i<4;i++) acc[i] = zero;

  int arow = w*16 + (lane&15);
  int af0 = arow*64 + ((((lane>>4)  ) ^ (arow & 7)) * 8);
  int af1 = arow*64 + (((4+(lane>>4)) ^ (arow & 7)) * 8);
  int bf0[4], bf1[4];
#pragma unroll
  for(int nt=0;nt<4;nt++){
    int br = nt*16 + (lane&15);
    bf0[nt] = br*64 + ((((lane>>4)  ) ^ (br & 7)) * 8);
    bf1[nt] = br*64 + (((4+(lane>>4)) ^ (br & 7)) * 8);
  }

  size_t koff = (size_t)s_start * 64;
  uint4 ra0 = *(const uint4*)(aptr0 + koff);
  uint4 ra1 = *(const uint4*)(aptr1 + koff);
  uint4 rb0 = *(const uint4*)(bptr0 + koff);
  uint4 rb1 = *(const uint4*)(bptr1 + koff);

  for(int s=0; s<s_count; s++){
    int cur = s & 1;
    *(uint4*)(As[cur] + d0) = ra0;
    *(uint4*)(As[cur] + d1) = ra1;
    *(uint4*)(Bs[cur] + d0) = rb0;
    *(uint4*)(Bs[cur] + d1) = rb1;
    koff += 64;
    if(s+1 < s_count){
      ra0 = *(const uint4*)(aptr0 + koff);
      ra1 = *(const uint4*)(aptr1 + koff);
      rb0 = *(const uint4*)(bptr0 + koff);
      rb1 = *(const uint4*)(bptr1 + koff);
    }
    __syncthreads();
    short8 a0 = *(const short8*)(As[cur] + af0);
    short8 a1 = *(const short8*)(As[cur] + af1);
    short8 b0h0 = *(const short8*)(Bs[cur] + bf0[0]);
    short8 b1h0 = *(const short8*)(Bs[cur] + bf0[1]);
    short8 b2h0 = *(const short8*)(Bs[cur] + bf0[2]);
    short8 b3h0 = *(const short8*)(Bs[cur] + bf0[3]);
    short8 b0h1 = *(const short8*)(Bs[cur] + bf1[0]);
    short8 b1h1 = *(const short8*)(Bs[cur] + bf1[1]);
    short8 b2h1 = *(const short8*)(Bs[cur] + bf1[2]);
    short8 b3h1 = *(const short8*)(Bs[cur] + bf1[3]);
    __builtin_amdgcn_s_setprio(1);
    acc[0] = __builtin_amdgcn_mfma_f32_16x16x32_bf16(a0, b0h0, acc[0], 0, 0, 0);
    acc[1] = __builtin_amdgcn_mfma_f32_16x16x32_bf16(a0, b1h0, acc[1], 0, 0, 0);
    acc[2] = __builtin_amdgcn_mfma_f32_16x16x32_bf16(a0, b2h0, acc[2], 0, 0, 0);
    acc[3] = __builtin_amdgcn_mfma_f32_16x16x32_bf16(a0, b3h0, acc[3], 0, 0, 0);
    acc[0] = __builtin_amdgcn_mfma_f32_16x16x32_bf16(a1, b0h1, acc[0], 0, 0, 0);
    acc[1] = __builtin_amdgcn_mfma_f32_16x16x32_bf16(a1, b1h1, acc[1], 0, 0, 0);
    acc[2] = __builtin_amdgcn_mfma_f32_16x16x32_bf16(a1, b2h1, acc[2], 0, 0, 0);
    acc[3] = __builtin_amdgcn_mfma_f32_16x16x32_bf16(a1, b3h1, acc[3], 0, 0, 0);
    __builtin_amdgcn_s_setprio(0);
  }
  float* po = part + (size_t)bz*NB*500;
#pragma unroll
  for(int nt=0;nt<4;nt++){
#pragma unroll
    for(int reg=0;reg<4;reg++){
      int m = m0 + w*16 + (lane>>4)*4 + reg;
      int c = n0 + nt*16 + (lane&15);
      if(c < 500) po[(size_t)m*500 + c] = acc[nt][reg];
    }
  }
}

// ---------- reduce partials -> actT[c][n] ----------
__global__ void mb_reduce_kernel(const float* __restrict__ part, float* __restrict__ actT){
  int idx = blockIdx.x*256 + threadIdx.x;   // n*500+c
  float s = 0.f;
#pragma unroll
  for(int z=0;z<SPLITK;z++) s += part[(size_t)z*NB*500 + idx];
  int n = idx/500, c = idx - n*500;
  actT[(size_t)c*NB + n] = s;
}

// ---------- minibatch features ----------
__global__ __launch_bounds__(256)
void feats_kernel(const float* __restrict__ actT, float* __restrict__ feats){
  __shared__ float ash[4][50];
  __shared__ float pred[4][4];
  int i0 = blockIdx.x*4, k0 = blockIdx.y*10;
  int tid = threadIdx.x, lane = tid & 63, wv = tid >> 6;
  if(tid < 200){
    int ii = tid/50, c = tid - ii*50;
    ash[ii][c] = actT[(size_t)(k0*5+c)*NB + i0 + ii];
  }
  __syncthreads();
  const float LOG2E = 1.4426950408889634f;
  int j1 = tid, j2 = tid + 256;
  for(int kk=0; kk<10; kk++){
    const float* r0 = actT + (size_t)(k0+kk)*5*NB;
    float xa0=r0[j1], xa1=r0[NB+j1], xa2=r0[2*NB+j1], xa3=r0[3*NB+j1], xa4=r0[4*NB+j1];
    float xb0=r0[j2], xb1=r0[NB+j2], xb2=r0[2*NB+j2], xb3=r0[3*NB+j2], xb4=r0[4*NB+j2];
    float f[4];
#pragma unroll
    for(int ii=0; ii<4; ii++){
      float a0=ash[ii][kk*5+0], a1=ash[ii][kk*5+1], a2=ash[ii][kk*5+2],
            a3=ash[ii][kk*5+3], a4=ash[ii][kk*5+4];
      float la = fabsf(xa0-a0)+fabsf(xa1-a1)+fabsf(xa2-a2)+fabsf(xa3-a3)+fabsf(xa4-a4);
      float lb = fabsf(xb0-a0)+fabsf(xb1-a1)+fabsf(xb2-a2)+fabsf(xb3-a3)+fabsf(xb4-a4);
      f[ii] = exp2f(-LOG2E*la) + exp2f(-LOG2E*lb);
    }
#pragma unroll
    for(int ii=0; ii<4; ii++){
      float v = f[ii];
#pragma unroll
      for(int s=32; s>0; s>>=1) v += __shfl_down(v, s, 64);
      if(lane==0) pred[wv][ii] = v;
    }
    __syncthreads();
    if(tid < 4){
      float v = pred[0][tid] + pred[1][tid] + pred[2][tid] + pred[3][tid];
      feats[(size_t)(i0+tid)*NUMK + k0 + kk] = v;
    }
    __syncthreads();
  }
}

// ---------- final ----------
__global__ void final_kernel(const unsigned short* __restrict__ flatbf, const float* __restrict__ feats,
                             const int* __restrict__ condition, const float* __restrict__ emb,
                             const float* __restrict__ cond_w, const float* __restrict__ cond_b,
                             const float* __restrict__ fc_w, const float* __restrict__ fc_b,
                             float* __restrict__ out){
  __shared__ float red[4];
  int n = blockIdx.x, tid = threadIdx.x;
  float s = 0.f;
  const unsigned short* fr = flatbf + (size_t)n*FLATSZ;
  for(int q=tid; q<FLATSZ/8; q+=256){
    uint4 u = *(const uint4*)(fr + q*8);
    float4 wa = *(const float4*)(fc_w + q*8);
    float4 wb = *(const float4*)(fc_w + q*8 + 4);
    s += bf2f((unsigned short)(u.x & 0xffff))*wa.x + bf2f((unsigned short)(u.x >> 16))*wa.y
       + bf2f((unsigned short)(u.y & 0xffff))*wa.z + bf2f((unsigned short)(u.y >> 16))*wa.w
       + bf2f((unsigned short)(u.z & 0xffff))*wb.x + bf2f((unsigned short)(u.z >> 16))*wb.y
       + bf2f((unsigned short)(u.w & 0xffff))*wb.z + bf2f((unsigned short)(u.w >> 16))*wb.w;
  }
  for(int k=tid;k<NUMK;k+=256) s += feats[n*NUMK+k]*fc_w[FLATSZ+k];
  float ce = emb[condition[n]];
  for(int j=tid;j<50;j+=256) s += (ce*cond_w[j]+cond_b[j])*fc_w[FLATSZ+NUMK+j];
  s = block_reduce_sum(s, red);
  if(tid==0) out[n] = s + fc_b[0];
}

extern "C" void kernel_launch(void* const* d_in, const int* in_sizes, int n_in,
                              void* d_out, int out_size, void* d_ws, size_t ws_size,
                              hipStream_t stream) {
  const float* ecg   = (const float*)d_in[0];
  const int*   cond  = (const int*)  d_in[1];
  const float* w1    = (const float*)d_in[2];
  const float* b1    = (const float*)d_in[3];
  const float* u1    = (const float*)d_in[4];
  const float* w2    = (const float*)d_in[5];
  const float* b2    = (const float*)d_in[6];
  const float* u2    = (const float*)d_in[7];
  const float* w3    = (const float*)d_in[8];
  const float* b3    = (const float*)d_in[9];
  const float* u3    = (const float*)d_in[10];
  const float* emb   = (const float*)d_in[11];
  const float* condw = (const float*)d_in[12];
  const float* condb = (const float*)d_in[13];
  const float* mbw   = (const float*)d_in[14];
  const float* fcw   = (const float*)d_in[15];
  const float* fcb   = (const float*)d_in[16];

  float* ws = (float*)d_ws;
  float* scale = ws;                                      // 0..16
  float* ssbuf = ws + 16;
  float* Sunbuf= ws + 24;
  float* v_all = ws + 32;                                 // ends 1648
  unsigned short* w1p  = (unsigned short*)(ws + 1648);    // -> 2672
  unsigned short* w2p  = (unsigned short*)(ws + 2672);    // -> 31344
  unsigned short* w3p  = (unsigned short*)(ws + 31344);   // -> 178800
  unsigned short* mbwT = (unsigned short*)(ws + 178800);  // 512 rows x 20224 bf16
  float* part  = ws + 5454448;                            // 16*512*500 f -> 9,550,448
  float* actT  = ws + 9550448;                            // 256,000 f -> 9,806,448
  float* feats = ws + 9806448;                            // 51,200 f -> 9,857,648
  unsigned short* flatbf = (unsigned short*)(ws + 9857648); // 5,177,344 f -> ends 15,034,992

  hipMemsetAsync((char*)d_ws + 64, 0, 64, stream);   // zero ssbuf/Sunbuf
  sn_pass1<<<8, 256, 0, stream>>>(w1,u1,w2,u2,w3,u3, v_all, ssbuf);
  sn_pass2<<<112, 256, 0, stream>>>(w1,w2,w3, v_all, Sunbuf);
  sn_final<<<1, 64, 0, stream>>>(ssbuf, Sunbuf, scale);
  wprep_kernel<<<1152, 256, 0, stream>>>(w1, w2, w3, scale, w1p, w2p, w3p);
  conv123_mfma<<<NB, 256, 0, stream>>>(ecg, w1p, b1, w2p, b2, w3p, b3, flatbf);
  mbw_transpose<<<dim3(632,16), 256, 0, stream>>>(mbw, mbwT);
  mb_gemm_mfma<<<dim3(8,8,SPLITK), 256, 0, stream>>>(flatbf, mbwT, part);
  mb_reduce_kernel<<<1000, 256, 0, stream>>>(part, actT);
  feats_kernel<<<dim3(128,10), 256, 0, stream>>>(actT, feats);
  final_kernel<<<NB, 256, 0, stream>>>(flatbf, feats, cond, emb, condw, condb, fcw, fcb, (float*)d_out);
}

// Round 13
// 278.845 us; speedup vs baseline: 2.7214x; 1.0725x over previous
//
#include <hip/hip_runtime.h>
#include <math.h>

#define NB 512
#define LIN 640
#define NLEADS 3
#define L1O 322
#define L2O 161
#define L3O 79
#define C1N 64
#define C2N 128
#define C3N 256
#define FLATSZ 20224   // 256*79
#define NUMK 100
#define DIMK 5
#define SPLITK 16

typedef __attribute__((ext_vector_type(8))) short short8;
typedef __attribute__((ext_vector_type(4))) float f32x4;

__device__ __forceinline__ unsigned short f2bf(float x){
  unsigned u = __builtin_bit_cast(unsigned, x);
  unsigned r = u + 0x7FFFu + ((u >> 16) & 1u);
  return (unsigned short)(r >> 16);
}
__device__ __forceinline__ float bf2f(unsigned short x){
  unsigned u = ((unsigned)x) << 16;
  return __builtin_bit_cast(float, u);
}

__device__ __forceinline__ float block_reduce_sum(float val, float* red){
#pragma unroll
  for(int off=32; off>0; off>>=1) val += __shfl_down(val, off, 64);
  int lane = threadIdx.x & 63;
  int wv = threadIdx.x >> 6;
  if(lane==0) red[wv] = val;
  __syncthreads();
  int nw = blockDim.x >> 6;
  float r = red[0];
  for(int i=1;i<nw;i++) r += red[i];
  __syncthreads();
  return r;
}

// ---------- SN pass 1 (r23: partial-sum slots instead of atomics -> no memset) ----------
__global__ __launch_bounds__(256)
void sn_pass1(const float* __restrict__ w1, const float* __restrict__ u1,
              const float* __restrict__ w2, const float* __restrict__ u2,
              const float* __restrict__ w3, const float* __restrict__ u3,
              float* __restrict__ v_all, float* __restrict__ ss_part){
  __shared__ float red[4];
  int b = blockIdx.x, tid = threadIdx.x;
  const float* w; const float* u; int O, C, off, c;
  if(b==0){ w=w1; u=u1; O=64;  C=15;   off=0;   c=tid; }
  else if(b<3){ w=w2; u=u2; O=128; C=448; off=16;  c=(b-1)*256+tid; }
  else { w=w3; u=u3; O=256; C=1152; off=464; c=(b-3)*256+tid; }
  float vv = 0.f;
  if(c < C){
    for(int o=0;o<O;o+=4){
      vv += w[(o+0)*C+c]*u[o+0] + w[(o+1)*C+c]*u[o+1]
          + w[(o+2)*C+c]*u[o+2] + w[(o+3)*C+c]*u[o+3];
    }
    v_all[off + c] = vv;
  }
  float ps = (c < C) ? vv*vv : 0.f;
  float tot = block_reduce_sum(ps, red);
  if(tid==0) ss_part[b] = tot;
}

// ---------- SN pass 2 (r23: per-block partial Sun, r20-verified pattern) ----------
__global__ __launch_bounds__(256)
void sn_pass2(const float* __restrict__ w1, const float* __restrict__ w2,
              const float* __restrict__ w3, const float* __restrict__ v_all,
              float* __restrict__ Sun_part){
  __shared__ float red[4];
  int b = blockIdx.x, tid = threadIdx.x;
  int lane = tid & 63, wv = tid >> 6;
  const float* w; int C, off, o;
  if(b < 16){ w=w1; C=15;   off=0;   o=b*4+wv; }
  else if(b < 48){ w=w2; C=448; off=16;  o=(b-16)*4+wv; }
  else { w=w3; C=1152; off=464; o=(b-48)*4+wv; }
  float t = 0.f;
  for(int c=lane; c<C; c+=64) t += w[o*C+c]*v_all[off+c];
#pragma unroll
  for(int s=32; s>0; s>>=1) t += __shfl_down(t, s, 64);
  if(lane==0) red[wv] = t*t;
  __syncthreads();
  if(tid==0) Sun_part[b] = red[0] + red[1] + red[2] + red[3];
}

// ---------- r23: merged weight-prep (scales from partials, r17-proven fold) + mbw transpose.
// Blocks 0..1151: wprep. Blocks 1152..11263: transpose (bodies verbatim from verified kernels).
// Independent work overlaps in one dispatch; saves 3 launches total vs r22 (memset, sn_final,
// separate transpose).
__global__ __launch_bounds__(256)
void prep_trans_kernel(const float* __restrict__ w1, const float* __restrict__ w2,
                       const float* __restrict__ w3, const float* __restrict__ ss_part,
                       const float* __restrict__ Sun_part,
                       unsigned short* __restrict__ w1p, unsigned short* __restrict__ w2p,
                       unsigned short* __restrict__ w3p,
                       const float* __restrict__ mbw, unsigned short* __restrict__ mbwT){
  __shared__ unsigned short tile[32][36];
  int bid = blockIdx.x, tid = threadIdx.x;

  if(bid < 1152){
    float ssv[3], Sunv[3];
    ssv[0] = ss_part[0];
    ssv[1] = ss_part[1] + ss_part[2];
    ssv[2] = ss_part[3] + ss_part[4] + ss_part[5] + ss_part[6] + ss_part[7];
    Sunv[0] = 0.f; Sunv[1] = 0.f; Sunv[2] = 0.f;
    for(int b=0;b<16;b++)   Sunv[0] += Sun_part[b];
    for(int b=16;b<48;b++)  Sunv[1] += Sun_part[b];
    for(int b=48;b<112;b++) Sunv[2] += Sun_part[b];
    float sc[3];
#pragma unroll
    for(int i=0;i<3;i++){
      float inv = 1.f/(sqrtf(ssv[i])+1e-12f);
      float S = Sunv[i]*inv*inv;
      sc[i] = (sqrtf(S)+1e-12f)/S;
    }
    int idx = bid*256 + tid;
    if(idx < C1N*32){
      int o = idx >> 5, kk = idx & 31;
      w1p[idx] = (kk < 15) ? f2bf(w1[o*15+kk]*sc[0]) : 0;
    }
    if(idx < C2N*448){
      int o = idx / 448, k2 = idx - o*448;
      int r = k2 >> 6, i = k2 & 63;
      w2p[idx] = f2bf(w2[o*448 + i*7 + r]*sc[1]);
    }
    if(idx < C3N*1152){
      int o = idx / 1152, k2 = idx - o*1152;
      int r = k2 >> 7, i = k2 & 127;
      w3p[idx] = f2bf(w3[o*1152 + i*9 + r]*sc[2]);
    }
    return;
  }

  // transpose path (verbatim body)
  int tt = bid - 1152;
  int k0 = (tt % 632)*32, n0 = (tt / 632)*32;
  int r = tid >> 3, c4 = (tid & 7) * 4;
  int nbase = n0 + c4;
  if(nbase + 3 < 500){
    float4 v = *(const float4*)(mbw + (size_t)(k0+r)*500 + nbase);
    tile[r][c4+0] = f2bf(v.x);
    tile[r][c4+1] = f2bf(v.y);
    tile[r][c4+2] = f2bf(v.z);
    tile[r][c4+3] = f2bf(v.w);
  } else {
#pragma unroll
    for(int j=0;j<4;j++){
      int nn = nbase + j;
      float v = (nn < 500) ? mbw[(size_t)(k0+r)*500 + nn] : 0.f;
      tile[r][c4+j] = f2bf(v);
    }
  }
  __syncthreads();
  int nl = tid >> 3, kq = (tid & 7) * 4;
  unsigned short t0 = tile[kq+0][nl], t1 = tile[kq+1][nl];
  unsigned short t2 = tile[kq+2][nl], t3 = tile[kq+3][nl];
  uint2 p;
  p.x = (unsigned)t0 | ((unsigned)t1 << 16);
  p.y = (unsigned)t2 | ((unsigned)t3 << 16);
  *(uint2*)(mbwT + (size_t)(n0+nl)*FLATSZ + k0 + kq) = p;
}

// ---------- FUSED conv1+conv2+conv3 (r17, unchanged) ----------
__global__ __launch_bounds__(256, 2)
void conv123_mfma(const float* __restrict__ ecg, const unsigned short* __restrict__ w1p,
                  const float* __restrict__ b1, const unsigned short* __restrict__ w2p,
                  const float* __restrict__ b2, const unsigned short* __restrict__ w3p,
                  const float* __restrict__ b3, unsigned short* __restrict__ flatbf){
  __shared__ unsigned short y2buf[22712];   // even slab 84*136 @0; odd slab 83*136 @11424
  __shared__ unsigned short slabs[13600];   // y1 parity slabs (per tile): even [100][68] @0, odd @6800
  __shared__ unsigned short B1s[3328];      // [208][16] u16 — conv1 im2col (kk 0..15; 15=pad)
  int n = blockIdx.x, tid = threadIdx.x;
  int lane = tid & 63, w = tid >> 6;

  if(tid < 136){
    y2buf[tid] = 0;
    y2buf[82*136 + tid] = 0;
    y2buf[83*136 + tid] = 0;
    y2buf[11424 + tid] = 0;
    y2buf[11424 + 81*136 + tid] = 0;
    y2buf[11424 + 82*136 + tid] = 0;
  }

  const float* eb = ecg + (size_t)n*LIN*NLEADS;
  f32x4 zero4 = {0.f,0.f,0.f,0.f};

  for(int tile=0; tile<2; tile++){
    int c0    = tile ? 189 : 0;
    int tbase = tile ? 96  : 0;
    int suboff= tile ? -94 : 2;

    __syncthreads();
    {
      uint4 z = {0u,0u,0u,0u};
      uint4* zd = (uint4*)slabs;
#pragma unroll
      for(int q=0;q<7;q++){
        int f = q*256 + tid;
        if(f < 1700) zd[f] = z;
      }
    }
    if(tid < 208){
      int t1 = c0 + tid;
      int p0 = 2*t1 - 4;
      unsigned short row16[16];
      row16[15] = 0;
      if(p0 >= 0 && p0 <= 635){
        const float* f = eb + p0*NLEADS;
#pragma unroll
        for(int rp=0; rp<5; rp++)
#pragma unroll
          for(int i=0;i<3;i++)
            row16[i*5+rp] = f2bf(f[3*rp+i]);
      } else {
#pragma unroll
        for(int rp=0; rp<5; rp++){
          int p = p0 + rp;
          bool ok = (unsigned)p < (unsigned)LIN;
#pragma unroll
          for(int i=0;i<3;i++)
            row16[i*5+rp] = ok ? f2bf(eb[p*NLEADS+i]) : (unsigned short)0;
        }
      }
      unsigned* dst = (unsigned*)(B1s + tid*16);
#pragma unroll
      for(int q=0;q<8;q++)
        dst[q] = (unsigned)row16[2*q] | ((unsigned)row16[2*q+1] << 16);
    }
    __syncthreads();

    // conv1 MFMA -> y1 parity slabs
    {
      short8 a1 = *(const short8*)(w1p + ((w*16 + (lane&15))<<5) + (lane>>4)*8);
      int cfrag = lane >> 4;
#pragma unroll
      for(int half=0; half<2; half++){
        int nt0 = half*7, ntc = half ? 6 : 7;
        f32x4 c1[7];
        for(int j=0;j<ntc;j++){
          int tp = (nt0+j)*16 + (lane&15);
          short8 b = {0,0,0,0,0,0,0,0};
          if(cfrag < 2) b = *(const short8*)(B1s + tp*16 + cfrag*8);
          c1[j] = __builtin_amdgcn_mfma_f32_16x16x32_bf16(a1, b, zero4, 0, 0, 0);
        }
#pragma unroll
        for(int reg=0;reg<4;reg++){
          int o = w*16 + (lane>>4)*4 + reg;
          float bias = b1[o];
          for(int j=0;j<ntc;j++){
            int tp = (nt0+j)*16 + (lane&15);
            int t1 = c0 + tp;
            int sub = (t1>>1) + suboff;
            if(t1 < L1O && sub < 100){
              float v = c1[j][reg] + bias;
              v = v>=0.f ? v : 0.2f*v;
              slabs[((t1&1)?6800:0) + sub*68 + o] = f2bf(v);
            }
          }
        }
      }
    }
    __syncthreads();

    // conv2 K-loop -> epilogue into y2buf
    f32x4 acc[2][6];
#pragma unroll
    for(int i=0;i<2;i++)
#pragma unroll
      for(int j=0;j<6;j++) acc[i][j] = zero4;

    const unsigned short* w2base = w2p + ((size_t)(w*2*16 + (lane&15)))*448 + (lane>>4)*8;
    short8 a_cur[2];
    a_cur[0] = *(const short8*)(w2base);
    a_cur[1] = *(const short8*)(w2base + 16*448);

    for(int ck=0; ck<14; ck++){
      short8 a_nxt[2];
      if(ck < 13){
        a_nxt[0] = *(const short8*)(w2base + (ck+1)*32);
        a_nxt[1] = *(const short8*)(w2base + 16*448 + (ck+1)*32);
      }
      int r = ck >> 1, i0 = (ck & 1)*32;
      int p = (r+1) & 1;
      int m = ((r-3) - p) >> 1;
      int base = (p?6800:0) + (m+2 + (lane&15))*68 + i0 + (lane>>4)*8;
      short8 b[6];
#pragma unroll
      for(int nt=0;nt<6;nt++)
        b[nt] = *(const short8*)(slabs + base + nt*16*68);
      __builtin_amdgcn_s_setprio(1);
#pragma unroll
      for(int mm=0;mm<2;mm++)
#pragma unroll
        for(int nt=0;nt<6;nt++)
          acc[mm][nt] = __builtin_amdgcn_mfma_f32_16x16x32_bf16(a_cur[mm], b[nt], acc[mm][nt], 0, 0, 0);
      __builtin_amdgcn_s_setprio(0);
      if(ck < 13){ a_cur[0] = a_nxt[0]; a_cur[1] = a_nxt[1]; }
    }

#pragma unroll
    for(int mm=0;mm<2;mm++){
#pragma unroll
      for(int reg=0;reg<4;reg++){
        int o = (w*2+mm)*16 + (lane>>4)*4 + reg;
        float bias = b2[o];
#pragma unroll
        for(int nt=0;nt<6;nt++){
          int tl = nt*16 + (lane&15);
          int t = tbase + tl;
          if(t < L2O){
            float v = acc[mm][nt][reg] + bias;
            v = v>=0.f ? v : 0.2f*v;
            y2buf[((t&1)?11424:0) + ((t>>1)+1)*136 + o] = f2bf(v);
          }
        }
      }
    }
  } // tile loop
  __syncthreads();

  // conv3 phase
  f32x4 acc3[4][5];
#pragma unroll
  for(int i=0;i<4;i++)
#pragma unroll
    for(int j=0;j<5;j++) acc3[i][j] = zero4;

  const unsigned short* wbase = w3p + ((size_t)(w*64) + (lane&15))*1152 + (lane>>4)*8;
  short8 abuf[3][4];
#pragma unroll
  for(int d=0; d<2; d++)
#pragma unroll
    for(int mm=0;mm<4;mm++)
      abuf[d][mm] = *(const short8*)(wbase + mm*16*1152 + d*32);

#pragma unroll
  for(int ck=0; ck<36; ck++){
    const int cur = ck % 3;
    const int nxt = (ck+2) % 3;
    if(ck+2 < 36){
      int kc = (ck+2)*32;
#pragma unroll
      for(int mm=0;mm<4;mm++)
        abuf[nxt][mm] = *(const short8*)(wbase + mm*16*1152 + kc);
    }
    int r = ck >> 2, i0 = (ck & 3) * 32;
    int cbase = ((r & 1) ? 11424 : 0) + (r >> 1)*136 + i0 + (lane>>4)*8;
    short8 b[5];
#pragma unroll
    for(int nt=0;nt<5;nt++){
      int t = nt*16 + (lane&15);
      b[nt] = *(const short8*)(y2buf + cbase + t*136);
    }
    __builtin_amdgcn_s_setprio(1);
#pragma unroll
    for(int mm=0;mm<4;mm++)
#pragma unroll
      for(int nt=0;nt<5;nt++)
        acc3[mm][nt] = __builtin_amdgcn_mfma_f32_16x16x32_bf16(abuf[cur][mm], b[nt], acc3[mm][nt], 0, 0, 0);
    __builtin_amdgcn_s_setprio(0);
  }
#pragma unroll
  for(int mm=0;mm<4;mm++){
#pragma unroll
    for(int reg=0;reg<4;reg++){
      int o = w*64 + mm*16 + (lane>>4)*4 + reg;
      float bias = b3[o];
#pragma unroll
      for(int nt=0;nt<5;nt++){
        int t = nt*16 + (lane&15);
        if(t < L3O){
          float v = acc3[mm][nt][reg] + bias;
          v = v>=0.f ? v : 0.2f*v;
          flatbf[(size_t)n*FLATSZ + o*L3O + t] = f2bf(v);
        }
      }
    }
  }
}

// ---------- split-K MFMA GEMM (r19, unchanged) ----------
__global__ __launch_bounds__(256, 4)
void mb_gemm_mfma(const unsigned short* __restrict__ flatbf, const unsigned short* __restrict__ mbwT,
                  float* __restrict__ part){
  __shared__ unsigned short As[2][4096];   // [64][64] elems, swizzled
  __shared__ unsigned short Bs[2][4096];
  int tid = threadIdx.x;
  int lane = tid & 63, w = tid >> 6;
  int m0 = blockIdx.x*64, n0 = blockIdx.y*64, bz = blockIdx.z;
  int s_start = bz*19 + (bz < 12 ? bz : 12);
  int s_count = 19 + (bz < 12 ? 1 : 0);

  int r0 = tid >> 3,        c80 = tid & 7;
  int r1 = 32 + (tid >> 3), c81 = tid & 7;
  const unsigned short* aptr0 = flatbf + (size_t)(m0+r0)*FLATSZ + c80*8;
  const unsigned short* aptr1 = flatbf + (size_t)(m0+r1)*FLATSZ + c81*8;
  const unsigned short* bptr0 = mbwT  + (size_t)(n0+r0)*FLATSZ + c80*8;
  const unsigned short* bptr1 = mbwT  + (size_t)(n0+r1)*FLATSZ + c81*8;
  int d0 = r0*64 + ((c80 ^ (r0 & 7)) * 8);
  int d1 = r1*64 + ((c81 ^ (r1 & 7)) * 8);

  f32x4 zero = {0.f,0.f,0.f,0.f};
  f32x4 acc[4];
#pragma unroll
  for(int i=0;i<4;i++) acc[i] = zero;

  int arow = w*16 + (lane&15);
  int af0 = arow*64 + ((((lane>>4)  ) ^ (arow & 7)) * 8);
  int af1 = arow*64 + (((4+(lane>>4)) ^ (arow & 7)) * 8);
  int bf0[4], bf1[4];
#pragma unroll
  for(int nt=0;nt<4;nt++){
    int br = nt*16 + (lane&15);
    bf0[nt] = br*64 + ((((lane>>4)  ) ^ (br & 7)) * 8);
    bf1[nt] = br*64 + (((4+(lane>>4)) ^ (br & 7)) * 8);
  }

  size_t koff = (size_t)s_start * 64;
  uint4 ra0 = *(const uint4*)(aptr0 + koff);
  uint4 ra1 = *(const uint4*)(aptr1 + koff);
  uint4 rb0 = *(const uint4*)(bptr0 + koff);
  uint4 rb1 = *(const uint4*)(bptr1 + koff);

  for(int s=0; s<s_count; s++){
    int cur = s & 1;
    *(uint4*)(As[cur] + d0) = ra0;
    *(uint4*)(As[cur] + d1) = ra1;
    *(uint4*)(Bs[cur] + d0) = rb0;
    *(uint4*)(Bs[cur] + d1) = rb1;
    koff += 64;
    if(s+1 < s_count){
      ra0 = *(const uint4*)(aptr0 + koff);
      ra1 = *(const uint4*)(aptr1 + koff);
      rb0 = *(const uint4*)(bptr0 + koff);
      rb1 = *(const uint4*)(bptr1 + koff);
    }
    __syncthreads();
    short8 a0 = *(const short8*)(As[cur] + af0);
    short8 a1 = *(const short8*)(As[cur] + af1);
    short8 b0h0 = *(const short8*)(Bs[cur] + bf0[0]);
    short8 b1h0 = *(const short8*)(Bs[cur] + bf0[1]);
    short8 b2h0 = *(const short8*)(Bs[cur] + bf0[2]);
    short8 b3h0 = *(const short8*)(Bs[cur] + bf0[3]);
    short8 b0h1 = *(const short8*)(Bs[cur] + bf1[0]);
    short8 b1h1 = *(const short8*)(Bs[cur] + bf1[1]);
    short8 b2h1 = *(const short8*)(Bs[cur] + bf1[2]);
    short8 b3h1 = *(const short8*)(Bs[cur] + bf1[3]);
    __builtin_amdgcn_s_setprio(1);
    acc[0] = __builtin_amdgcn_mfma_f32_16x16x32_bf16(a0, b0h0, acc[0], 0, 0, 0);
    acc[1] = __builtin_amdgcn_mfma_f32_16x16x32_bf16(a0, b1h0, acc[1], 0, 0, 0);
    acc[2] = __builtin_amdgcn_mfma_f32_16x16x32_bf16(a0, b2h0, acc[2], 0, 0, 0);
    acc[3] = __builtin_amdgcn_mfma_f32_16x16x32_bf16(a0, b3h0, acc[3], 0, 0, 0);
    acc[0] = __builtin_amdgcn_mfma_f32_16x16x32_bf16(a1, b0h1, acc[0], 0, 0, 0);
    acc[1] = __builtin_amdgcn_mfma_f32_16x16x32_bf16(a1, b1h1, acc[1], 0, 0, 0);
    acc[2] = __builtin_amdgcn_mfma_f32_16x16x32_bf16(a1, b2h1, acc[2], 0, 0, 0);
    acc[3] = __builtin_amdgcn_mfma_f32_16x16x32_bf16(a1, b3h1, acc[3], 0, 0, 0);
    __builtin_amdgcn_s_setprio(0);
  }
  float* po = part + (size_t)bz*NB*500;
#pragma unroll
  for(int nt=0;nt<4;nt++){
#pragma unroll
    for(int reg=0;reg<4;reg++){
      int m = m0 + w*16 + (lane>>4)*4 + reg;
      int c = n0 + nt*16 + (lane&15);
      if(c < 500) po[(size_t)m*500 + c] = acc[nt][reg];
    }
  }
}

// ---------- reduce partials -> actT[c][n] ----------
__global__ void mb_reduce_kernel(const float* __restrict__ part, float* __restrict__ actT){
  int idx = blockIdx.x*256 + threadIdx.x;   // n*500+c
  float s = 0.f;
#pragma unroll
  for(int z=0;z<SPLITK;z++) s += part[(size_t)z*NB*500 + idx];
  int n = idx/500, c = idx - n*500;
  actT[(size_t)c*NB + n] = s;
}

// ---------- minibatch features ----------
__global__ __launch_bounds__(256)
void feats_kernel(const float* __restrict__ actT, float* __restrict__ feats){
  __shared__ float ash[4][50];
  __shared__ float pred[4][4];
  int i0 = blockIdx.x*4, k0 = blockIdx.y*10;
  int tid = threadIdx.x, lane = tid & 63, wv = tid >> 6;
  if(tid < 200){
    int ii = tid/50, c = tid - ii*50;
    ash[ii][c] = actT[(size_t)(k0*5+c)*NB + i0 + ii];
  }
  __syncthreads();
  const float LOG2E = 1.4426950408889634f;
  int j1 = tid, j2 = tid + 256;
  for(int kk=0; kk<10; kk++){
    const float* r0 = actT + (size_t)(k0+kk)*5*NB;
    float xa0=r0[j1], xa1=r0[NB+j1], xa2=r0[2*NB+j1], xa3=r0[3*NB+j1], xa4=r0[4*NB+j1];
    float xb0=r0[j2], xb1=r0[NB+j2], xb2=r0[2*NB+j2], xb3=r0[3*NB+j2], xb4=r0[4*NB+j2];
    float f[4];
#pragma unroll
    for(int ii=0; ii<4; ii++){
      float a0=ash[ii][kk*5+0], a1=ash[ii][kk*5+1], a2=ash[ii][kk*5+2],
            a3=ash[ii][kk*5+3], a4=ash[ii][kk*5+4];
      float la = fabsf(xa0-a0)+fabsf(xa1-a1)+fabsf(xa2-a2)+fabsf(xa3-a3)+fabsf(xa4-a4);
      float lb = fabsf(xb0-a0)+fabsf(xb1-a1)+fabsf(xb2-a2)+fabsf(xb3-a3)+fabsf(xb4-a4);
      f[ii] = exp2f(-LOG2E*la) + exp2f(-LOG2E*lb);
    }
#pragma unroll
    for(int ii=0; ii<4; ii++){
      float v = f[ii];
#pragma unroll
      for(int s=32; s>0; s>>=1) v += __shfl_down(v, s, 64);
      if(lane==0) pred[wv][ii] = v;
    }
    __syncthreads();
    if(tid < 4){
      float v = pred[0][tid] + pred[1][tid] + pred[2][tid] + pred[3][tid];
      feats[(size_t)(i0+tid)*NUMK + k0 + kk] = v;
    }
    __syncthreads();
  }
}

// ---------- final ----------
__global__ void final_kernel(const unsigned short* __restrict__ flatbf, const float* __restrict__ feats,
                             const int* __restrict__ condition, const float* __restrict__ emb,
                             const float* __restrict__ cond_w, const float* __restrict__ cond_b,
                             const float* __restrict__ fc_w, const float* __restrict__ fc_b,
                             float* __restrict__ out){
  __shared__ float red[4];
  int n = blockIdx.x, tid = threadIdx.x;
  float s = 0.f;
  const unsigned short* fr = flatbf + (size_t)n*FLATSZ;
  for(int q=tid; q<FLATSZ/8; q+=256){
    uint4 u = *(const uint4*)(fr + q*8);
    float4 wa = *(const float4*)(fc_w + q*8);
    float4 wb = *(const float4*)(fc_w + q*8 + 4);
    s += bf2f((unsigned short)(u.x & 0xffff))*wa.x + bf2f((unsigned short)(u.x >> 16))*wa.y
       + bf2f((unsigned short)(u.y & 0xffff))*wa.z + bf2f((unsigned short)(u.y >> 16))*wa.w
       + bf2f((unsigned short)(u.z & 0xffff))*wb.x + bf2f((unsigned short)(u.z >> 16))*wb.y
       + bf2f((unsigned short)(u.w & 0xffff))*wb.z + bf2f((unsigned short)(u.w >> 16))*wb.w;
  }
  for(int k=tid;k<NUMK;k+=256) s += feats[n*NUMK+k]*fc_w[FLATSZ+k];
  float ce = emb[condition[n]];
  for(int j=tid;j<50;j+=256) s += (ce*cond_w[j]+cond_b[j])*fc_w[FLATSZ+NUMK+j];
  s = block_reduce_sum(s, red);
  if(tid==0) out[n] = s + fc_b[0];
}

extern "C" void kernel_launch(void* const* d_in, const int* in_sizes, int n_in,
                              void* d_out, int out_size, void* d_ws, size_t ws_size,
                              hipStream_t stream) {
  const float* ecg   = (const float*)d_in[0];
  const int*   cond  = (const int*)  d_in[1];
  const float* w1    = (const float*)d_in[2];
  const float* b1    = (const float*)d_in[3];
  const float* u1    = (const float*)d_in[4];
  const float* w2    = (const float*)d_in[5];
  const float* b2    = (const float*)d_in[6];
  const float* u2    = (const float*)d_in[7];
  const float* w3    = (const float*)d_in[8];
  const float* b3    = (const float*)d_in[9];
  const float* u3    = (const float*)d_in[10];
  const float* emb   = (const float*)d_in[11];
  const float* condw = (const float*)d_in[12];
  const float* condb = (const float*)d_in[13];
  const float* mbw   = (const float*)d_in[14];
  const float* fcw   = (const float*)d_in[15];
  const float* fcb   = (const float*)d_in[16];

  float* ws = (float*)d_ws;
  float* ss_part  = ws + 16;                              // 8 slots
  float* v_all    = ws + 32;                              // 1616 f -> ends 1648
  float* Sun_part = ws + 1648;                            // 112 slots -> 1760
  unsigned short* w1p  = (unsigned short*)(ws + 1792);    // 1024 f -> 2816
  unsigned short* w2p  = (unsigned short*)(ws + 2816);    // 28672 f -> 31488
  unsigned short* w3p  = (unsigned short*)(ws + 31488);   // 147456 f -> 178944
  unsigned short* mbwT = (unsigned short*)(ws + 178944);  // 512x20224 bf16 -> 5,356,288
  float* part  = ws + 5454448;                            // 16*512*500 f -> 9,550,448
  float* actT  = ws + 9550448;                            // 256,000 f -> 9,806,448
  float* feats = ws + 9806448;                            // 51,200 f -> 9,857,648
  unsigned short* flatbf = (unsigned short*)(ws + 9857648); // 5,177,344 f -> ends 15,034,992

  sn_pass1<<<8, 256, 0, stream>>>(w1,u1,w2,u2,w3,u3, v_all, ss_part);
  sn_pass2<<<112, 256, 0, stream>>>(w1,w2,w3, v_all, Sun_part);
  prep_trans_kernel<<<11264, 256, 0, stream>>>(w1, w2, w3, ss_part, Sun_part,
                                               w1p, w2p, w3p, mbw, mbwT);
  conv123_mfma<<<NB, 256, 0, stream>>>(ecg, w1p, b1, w2p, b2, w3p, b3, flatbf);
  mb_gemm_mfma<<<dim3(8,8,SPLITK), 256, 0, stream>>>(flatbf, mbwT, part);
  mb_reduce_kernel<<<1000, 256, 0, stream>>>(part, actT);
  feats_kernel<<<dim3(128,10), 256, 0, stream>>>(actT, feats);
  final_kernel<<<NB, 256, 0, stream>>>(flatbf, feats, cond, emb, condw, condb, fcw, fcb, (float*)d_out);
}